// Round 5
// baseline (1668.644 us; speedup 1.0000x reference)
//
#include <hip/hip_runtime.h>
#include <math.h>

#define NN 50000      // nodes
#define GG 100        // graphs
#define NPGc 500      // nodes per graph
#define HH 256        // hidden
#define IND 128       // input dim

typedef __attribute__((ext_vector_type(8))) short short8v;  // 8 bf16
typedef __attribute__((ext_vector_type(4))) float f32x4;

__device__ __forceinline__ ushort f2bf(float f) {
    union { float f; unsigned u; } v; v.f = f;
    unsigned r = (v.u + 0x7fffu + ((v.u >> 16) & 1u)) >> 16;  // RNE
    return (ushort)r;
}
__device__ __forceinline__ float bf2f(ushort h) {
    union { unsigned u; float f; } v; v.u = ((unsigned)h) << 16;
    return v.f;
}

// LDS ushort-index swizzle: XOR 16B-granule bits with row&7 (T2, bank-conflict fix)
__device__ __forceinline__ int swz(int row, int kidx) { return kidx ^ ((row & 7) << 3); }

// ---------------------------------------------------------------------------
// Weight transpose+convert: src [K][N] f32 -> dst [N][K] bf16
// ---------------------------------------------------------------------------
__global__ void wcvt(const float* __restrict__ src, ushort* __restrict__ dst, int K, int N)
{
    int i = blockIdx.x * 256 + threadIdx.x;
    if (i < K * N) {
        int n = i / K, k = i % K;
        dst[i] = f2bf(src[(size_t)k * N + n]);
    }
}

// ---------------------------------------------------------------------------
// bf16 MFMA GEMM: C[M x 256] = A[M x K](f32, cvt on stage) @ Wt[N=256][K](bf16)
// tile 128x128, BK=64, 4 waves each 64x64. LDS XOR-swizzled.
// mode 0: C = acc (+bias). mode 1: gate epilogue.
// ---------------------------------------------------------------------------
__global__ __launch_bounds__(256)
void gemm_mfma(const float* __restrict__ A, const float* __restrict__ A2,
               const ushort* __restrict__ Wt, const float* __restrict__ bias,
               float* __restrict__ C, int M, int K, int lda, int mode,
               const float* __restrict__ hn, const float* __restrict__ fn,
               const float* __restrict__ prev)
{
    __shared__ ushort As[128][64];
    __shared__ ushort Bs[128][64];
    const int tid = threadIdx.x;
    const int lane = tid & 63;
    const int w = tid >> 6;
    const int wr = (w >> 1) * 64, wc = (w & 1) * 64;
    const int row0 = blockIdx.x * 128, col0 = blockIdx.y * 128;
    const int lr = lane & 15, lk = (lane >> 4) * 8;
    f32x4 acc[4][4] = {};

    for (int k0 = 0; k0 < K; k0 += 64) {
        __syncthreads();
        #pragma unroll
        for (int it = 0; it < 4; ++it) {           // stage A: 128x64, f32->bf16
            int c = it * 256 + tid;
            int row = c >> 3, col = (c & 7) * 8;
            int gr = row0 + row; if (gr > M - 1) gr = M - 1;
            const float* Ap = A; int kk = k0 + col;
            if (A2 != nullptr && kk >= 256) { Ap = A2; kk -= 256; }
            const float* s = &Ap[(size_t)gr * lda + kk];
            float4 v0 = *(const float4*)s;
            float4 v1 = *(const float4*)(s + 4);
            union { ushort u[8]; int4 q; } pk;
            pk.u[0] = f2bf(v0.x); pk.u[1] = f2bf(v0.y); pk.u[2] = f2bf(v0.z); pk.u[3] = f2bf(v0.w);
            pk.u[4] = f2bf(v1.x); pk.u[5] = f2bf(v1.y); pk.u[6] = f2bf(v1.z); pk.u[7] = f2bf(v1.w);
            *(int4*)&As[row][swz(row, col)] = pk.q;
        }
        #pragma unroll
        for (int it = 0; it < 4; ++it) {           // stage B: Wt rows col0..+127
            int c = it * 256 + tid;
            int n = c >> 3, k = (c & 7) * 8;
            *(int4*)&Bs[n][swz(n, k)] = *(const int4*)&Wt[(size_t)(col0 + n) * K + k0 + k];
        }
        __syncthreads();
        #pragma unroll
        for (int ks = 0; ks < 2; ++ks) {
            short8v av[4], bv[4];
            #pragma unroll
            for (int m = 0; m < 4; ++m) {
                int rr = wr + m * 16 + lr;
                av[m] = *(const short8v*)&As[rr][swz(rr, ks * 32 + lk)];
            }
            #pragma unroll
            for (int n = 0; n < 4; ++n) {
                int rr = wc + n * 16 + lr;
                bv[n] = *(const short8v*)&Bs[rr][swz(rr, ks * 32 + lk)];
            }
            #pragma unroll
            for (int m = 0; m < 4; ++m)
                #pragma unroll
                for (int n = 0; n < 4; ++n)
                    acc[m][n] = __builtin_amdgcn_mfma_f32_16x16x32_bf16(av[m], bv[n], acc[m][n], 0, 0, 0);
        }
    }
    const int fr = (lane >> 4) * 4;
    if (mode == 0) {
        #pragma unroll
        for (int n = 0; n < 4; ++n) {
            int col = col0 + wc + n * 16 + lr;
            float bb = bias ? bias[col] : 0.f;
            #pragma unroll
            for (int m = 0; m < 4; ++m) {
                int rbase = row0 + wr + m * 16 + fr;
                #pragma unroll
                for (int r = 0; r < 4; ++r) {
                    int row = rbase + r;
                    if (row < M) C[(size_t)row * HH + col] = acc[m][n][r] + bb;
                }
            }
        }
    } else {
        #pragma unroll
        for (int n = 0; n < 4; ++n) {
            int col = col0 + wc + n * 16 + lr;
            float gb = bias[col];
            #pragma unroll
            for (int m = 0; m < 4; ++m) {
                int rbase = row0 + wr + m * 16 + fr;
                #pragma unroll
                for (int r = 0; r < 4; ++r) {
                    int row = rbase + r;
                    if (row < M) {
                        size_t o = (size_t)row * HH + col;
                        float z = acc[m][n][r] + gb;
                        float s = 1.f / (1.f + expf(-z));
                        C[o] = s * hn[o] + (1.f - s) * fn[o] + prev[o];
                    }
                }
            }
        }
    }
}

// ---------------------------------------------------------------------------
// Row L2-normalize, emit bf16 hi/lo split
// ---------------------------------------------------------------------------
__global__ __launch_bounds__(256)
void row_norm_hl(const float* __restrict__ h, ushort* __restrict__ xh, ushort* __restrict__ xl)
{
    int n = blockIdx.x, c = threadIdx.x;
    float v = h[(size_t)n * HH + c];
    __shared__ float red[256];
    red[c] = v * v;
    __syncthreads();
    for (int s = 128; s > 0; s >>= 1) {
        if (c < s) red[c] += red[c + s];
        __syncthreads();
    }
    float norm = sqrtf(red[0]);
    float xn = v / (norm + 1e-12f);
    ushort hi = f2bf(xn);
    xh[(size_t)n * HH + c] = hi;
    xl[(size_t)n * HH + c] = f2bf(xn - bf2f(hi));
}

// ---------------------------------------------------------------------------
// top-3 helpers (exact top_k tie-breaking: value desc, index asc)
// ---------------------------------------------------------------------------
__device__ __forceinline__ bool tk_better(float va, int ia, float vb, int ib)
{
    return (va > vb) || (va == vb && ia < ib);
}

__device__ __forceinline__ void ins3(float v, int i,
                                     float& a0, int& b0, float& a1, int& b1,
                                     float& a2, int& b2)
{
    if (tk_better(v, i, a0, b0))      { a2 = a1; b2 = b1; a1 = a0; b1 = b0; a0 = v; b0 = i; }
    else if (tk_better(v, i, a1, b1)) { a2 = a1; b2 = b1; a1 = v;  b1 = i; }
    else if (tk_better(v, i, a2, b2)) { a2 = v;  b2 = i; }
}

__device__ __forceinline__ void merge3(float& v0, float& v1, float& v2,
                                       int& i0, int& i1, int& i2, int off)
{
    float w0 = __shfl_xor(v0, off), w1 = __shfl_xor(v1, off), w2 = __shfl_xor(v2, off);
    int   j0 = __shfl_xor(i0, off), j1 = __shfl_xor(i1, off), j2 = __shfl_xor(i2, off);
    float avv[3] = { v0, v1, v2 }, bvv[3] = { w0, w1, w2 };
    int   aii[3] = { i0, i1, i2 }, bii[3] = { j0, j1, j2 };
    float rv[3]; int ri[3];
    int p = 0, q = 0;
    #pragma unroll
    for (int t = 0; t < 3; ++t) {
        bool takeA = tk_better(avv[p], aii[p], bvv[q], bii[q]);
        rv[t] = takeA ? avv[p] : bvv[q];
        ri[t] = takeA ? aii[p] : bii[q];
        if (takeA) ++p; else ++q;
    }
    v0 = rv[0]; v1 = rv[1]; v2 = rv[2];
    i0 = ri[0]; i1 = ri[1]; i2 = ri[2];
}

// ---------------------------------------------------------------------------
// simtopk_tile: one 128x128 sim tile per block (hi/lo bf16 MFMA, LDS-staged),
// emits per-row top-3 candidates for its col range. 16 tiles/graph.
// Block-id swizzle pins all 16 tiles of a graph to one XCD residue class.
// ---------------------------------------------------------------------------
__global__ __launch_bounds__(256, 2)
void simtopk_tile(const ushort* __restrict__ xnh, const ushort* __restrict__ xnl,
                  float* __restrict__ cval, int* __restrict__ cidx)
{
    __shared__ ushort Ash[128][64], Asl[128][64], Bsh[128][64], Bsl[128][64];  // 64KB
    const int flat = blockIdx.x;
    const int xcd = flat & 7, rest = flat >> 3;
    const int t = rest & 15;
    const int g = (rest >> 4) * 8 + xcd;
    if (g >= GG) return;
    const int row0 = (t & 3) * 128;
    const int cx = t >> 2;
    const int col0 = cx * 128;
    const int tid = threadIdx.x;
    const int lane = tid & 63;
    const int w = tid >> 6;
    const int wrow = w * 32;            // wave owns 32 rows (2 m-tiles)
    const int lr = lane & 15;
    const int hi4 = lane >> 4;
    const int lk = hi4 * 8;
    const size_t base = (size_t)g * NPGc * HH;

    float tv0[2][4], tv1[2][4], tv2[2][4];
    int   ti0[2][4], ti1[2][4], ti2[2][4];
    #pragma unroll
    for (int m = 0; m < 2; ++m)
        #pragma unroll
        for (int r = 0; r < 4; ++r) {
            tv0[m][r] = tv1[m][r] = tv2[m][r] = -2.f;
            ti0[m][r] = ti1[m][r] = ti2[m][r] = 0x7fffffff;
        }

    f32x4 acc[2][8] = {};
    for (int k0 = 0; k0 < HH; k0 += 64) {
        __syncthreads();
        #pragma unroll
        for (int it = 0; it < 4; ++it) {       // stage A rows (hi+lo)
            int c = it * 256 + tid;
            int rr = c >> 3, kc = (c & 7) * 8;
            int grow = row0 + rr; if (grow > NPGc - 1) grow = NPGc - 1;
            const size_t o = base + (size_t)grow * HH + k0 + kc;
            *(int4*)&Ash[rr][swz(rr, kc)] = *(const int4*)(xnh + o);
            *(int4*)&Asl[rr][swz(rr, kc)] = *(const int4*)(xnl + o);
        }
        #pragma unroll
        for (int it = 0; it < 4; ++it) {       // stage B cols (hi+lo)
            int c = it * 256 + tid;
            int rr = c >> 3, kc = (c & 7) * 8;
            int gcol = col0 + rr; if (gcol > NPGc - 1) gcol = NPGc - 1;
            const size_t o = base + (size_t)gcol * HH + k0 + kc;
            *(int4*)&Bsh[rr][swz(rr, kc)] = *(const int4*)(xnh + o);
            *(int4*)&Bsl[rr][swz(rr, kc)] = *(const int4*)(xnl + o);
        }
        __syncthreads();
        #pragma unroll
        for (int ks = 0; ks < 2; ++ks) {
            short8v ah[2], al[2], bh[8], bl[8];
            #pragma unroll
            for (int m = 0; m < 2; ++m) {
                int rr = wrow + m * 16 + lr;
                ah[m] = *(const short8v*)&Ash[rr][swz(rr, ks * 32 + lk)];
                al[m] = *(const short8v*)&Asl[rr][swz(rr, ks * 32 + lk)];
            }
            #pragma unroll
            for (int n = 0; n < 8; ++n) {
                int rr = n * 16 + lr;
                bh[n] = *(const short8v*)&Bsh[rr][swz(rr, ks * 32 + lk)];
                bl[n] = *(const short8v*)&Bsl[rr][swz(rr, ks * 32 + lk)];
            }
            #pragma unroll
            for (int m = 0; m < 2; ++m)
                #pragma unroll
                for (int n = 0; n < 8; ++n) {
                    acc[m][n] = __builtin_amdgcn_mfma_f32_16x16x32_bf16(ah[m], bh[n], acc[m][n], 0, 0, 0);
                    acc[m][n] = __builtin_amdgcn_mfma_f32_16x16x32_bf16(ah[m], bl[n], acc[m][n], 0, 0, 0);
                    acc[m][n] = __builtin_amdgcn_mfma_f32_16x16x32_bf16(al[m], bh[n], acc[m][n], 0, 0, 0);
                }
        }
    }
    // fold into top-3 (lane's col = col0 + n*16 + lr)
    #pragma unroll
    for (int m = 0; m < 2; ++m)
        #pragma unroll
        for (int n = 0; n < 8; ++n) {
            int col = col0 + n * 16 + lr;
            if (col < NPGc) {
                #pragma unroll
                for (int r = 0; r < 4; ++r)
                    ins3(acc[m][n][r], col,
                         tv0[m][r], ti0[m][r], tv1[m][r], ti1[m][r], tv2[m][r], ti2[m][r]);
            }
        }

    // merge across the 16 lanes sharing each row-quad
    #pragma unroll
    for (int m = 0; m < 2; ++m)
        #pragma unroll
        for (int r = 0; r < 4; ++r) {
            #pragma unroll
            for (int off = 1; off <= 8; off <<= 1)
                merge3(tv0[m][r], tv1[m][r], tv2[m][r],
                       ti0[m][r], ti1[m][r], ti2[m][r], off);
        }

    if (lr == 0) {
        #pragma unroll
        for (int m = 0; m < 2; ++m)
            #pragma unroll
            for (int r = 0; r < 4; ++r) {
                int row = row0 + wrow + m * 16 + hi4 * 4 + r;
                if (row < NPGc) {
                    size_t o = ((size_t)(g * NPGc + row)) * 12 + cx * 3;
                    cval[o + 0] = tv0[m][r]; cidx[o + 0] = ti0[m][r];
                    cval[o + 1] = tv1[m][r]; cidx[o + 1] = ti1[m][r];
                    cval[o + 2] = tv2[m][r]; cidx[o + 2] = ti2[m][r];
                }
            }
    }
}

// merge 4 col-tiles x 3 candidates -> exact top-3 -> fsrc
__global__ void cand_merge(const float* __restrict__ cval, const int* __restrict__ cidx,
                           int* __restrict__ fsrc)
{
    int row = blockIdx.x * 256 + threadIdx.x;
    if (row >= NN) return;
    int g = row / NPGc;
    float v0 = -3.f, v1 = -3.f, v2 = -3.f;
    int i0 = 0x7fffffff, i1 = 0x7fffffff, i2 = 0x7fffffff;
    #pragma unroll
    for (int j = 0; j < 12; ++j) {
        float v = cval[(size_t)row * 12 + j];
        int   i = cidx[(size_t)row * 12 + j];
        ins3(v, i, v0, i0, v1, i1, v2, i2);
    }
    fsrc[row * 3 + 0] = g * NPGc + i0;
    fsrc[row * 3 + 1] = g * NPGc + i1;
    fsrc[row * 3 + 2] = g * NPGc + i2;
}

// ---------------------------------------------------------------------------
// CSR build
// ---------------------------------------------------------------------------
__global__ void hist_kernel(const int* __restrict__ dst, int* __restrict__ cnt, int nE)
{
    int e = blockIdx.x * 256 + threadIdx.x;
    if (e < nE) atomicAdd(&cnt[dst[e]], 1);
}

__global__ void scan1_kernel(const int* __restrict__ in, int* __restrict__ out,
                             int* __restrict__ bsum, int n)
{
    __shared__ int sh[256];
    int t = threadIdx.x;
    int i = blockIdx.x * 256 + t;
    int v = (i < n) ? in[i] : 0;
    sh[t] = v;
    __syncthreads();
    for (int s = 1; s < 256; s <<= 1) {
        int tv = (t >= s) ? sh[t - s] : 0;
        __syncthreads();
        sh[t] += tv;
        __syncthreads();
    }
    if (i < n) out[i] = sh[t] - v;  // exclusive
    if (t == 255) bsum[blockIdx.x] = sh[255];
}

__global__ void scan2_kernel(int* __restrict__ bsum, int nb)
{
    __shared__ int sh[256];
    int t = threadIdx.x;
    int v = (t < nb) ? bsum[t] : 0;
    sh[t] = v;
    __syncthreads();
    for (int s = 1; s < 256; s <<= 1) {
        int tv = (t >= s) ? sh[t - s] : 0;
        __syncthreads();
        sh[t] += tv;
        __syncthreads();
    }
    if (t < nb) bsum[t] = sh[t] - v;  // exclusive block offsets
}

__global__ void scan3_kernel(int* __restrict__ out, const int* __restrict__ bsum, int n)
{
    int i = blockIdx.x * 256 + threadIdx.x;
    if (i < n) out[i] += bsum[blockIdx.x];
}

__global__ void fill_kernel(const int* __restrict__ src, const int* __restrict__ dst,
                            const int* __restrict__ row_ptr, int* __restrict__ cursor,
                            int* __restrict__ sorted_src, int nE)
{
    int e = blockIdx.x * 256 + threadIdx.x;
    if (e < nE) {
        int d = dst[e];
        int pos = row_ptr[d] + atomicAdd(&cursor[d], 1);
        sorted_src[pos] = src[e];
    }
}

__global__ void dinv_kernel(const int* __restrict__ cnt, float* __restrict__ dinv, int n)
{
    int i = blockIdx.x * 256 + threadIdx.x;
    if (i < n) dinv[i] = rsqrtf((float)cnt[i] + 1.0f);
}

// ---------------------------------------------------------------------------
// gcn32: LDS-resident GCN gather, block = (32-ch slice, graph).
// Stages the graph's 500x32 f32 message panel in LDS; every edge is an LDS hit.
// Fuses GraphNorm stats (S1/S2 per graph,channel) - no atomics, no memset.
// ---------------------------------------------------------------------------
__global__ __launch_bounds__(256)
void gcn32(const float* __restrict__ m, const int* __restrict__ row_ptr,
           const int* __restrict__ cnt, const int* __restrict__ srcs,
           const float* __restrict__ dinv, const float* __restrict__ bias,
           float* __restrict__ out, float* __restrict__ S1, float* __restrict__ S2)
{
    __shared__ float ml[NPGc][32];      // 64000 B
    __shared__ float dl[NPGc];
    __shared__ int   idxb[4][2][32];
    __shared__ float s1sh[4][32], s2sh[4][32];
    const int cc = blockIdx.x, g = blockIdx.y;
    const int tid = threadIdx.x, lane = tid & 63, w = tid >> 6;
    const int c2 = lane & 31, p = lane >> 5;
    const int nbase = g * NPGc;
    const int ch0 = cc * 32;

    #pragma unroll
    for (int i = 0; i < 16; ++i) {      // 500 rows x 8 float4
        int flat = i * 256 + tid;
        if (flat < NPGc * 8) {
            int row = flat >> 3, q = flat & 7;
            *(float4*)&ml[row][q * 4] =
                *(const float4*)&m[((size_t)(nbase + row)) * HH + ch0 + q * 4];
        }
    }
    for (int i = tid; i < NPGc; i += 256) dl[i] = dinv[nbase + i];
    __syncthreads();

    const float bb = bias[ch0 + c2];
    float s1 = 0.f, s2 = 0.f;
    const int n0w = w * 125, n1w = n0w + 125;
    for (int n0 = n0w; n0 < n1w; n0 += 2) {
        int myn = n0 + p;
        bool valid = myn < n1w;
        int nn = valid ? myn : n0;
        int s0 = row_ptr[nbase + nn];
        int dg = valid ? cnt[nbase + nn] : 0;
        float dn = dl[nn];
        float acc = ml[nn][c2] * dn;
        for (int bse = 0; bse < dg; bse += 32) {
            int chunk = dg - bse; if (chunk > 32) chunk = 32;
            if (c2 < chunk) idxb[w][p][c2] = srcs[s0 + bse + c2] - nbase;
            for (int e = 0; e < chunk; ++e) {
                int sl = idxb[w][p][e];
                acc += ml[sl][c2] * dl[sl];
            }
        }
        float outv = acc * dn + bb;
        if (valid) {
            out[((size_t)(nbase + nn)) * HH + ch0 + c2] = outv;
            s1 += outv; s2 += outv * outv;
        }
    }
    // combine node-parity halves (same channel at lane^32)
    s1 += __shfl_xor(s1, 32);
    s2 += __shfl_xor(s2, 32);
    if (p == 0) { s1sh[w][c2] = s1; s2sh[w][c2] = s2; }
    __syncthreads();
    if (tid < 32) {
        float a = s1sh[0][tid] + s1sh[1][tid] + s1sh[2][tid] + s1sh[3][tid];
        float b = s2sh[0][tid] + s2sh[1][tid] + s2sh[2][tid] + s2sh[3][tid];
        S1[g * HH + ch0 + tid] = a;
        S2[g * HH + ch0 + tid] = b;
    }
}

// fgcn32: knn-graph conv (deg = K+1 = 4, coef = 0.25), LDS-resident, fused stats
__global__ __launch_bounds__(256)
void fgcn32(const float* __restrict__ m, const int* __restrict__ fsrc,
            const float* __restrict__ bias, float* __restrict__ out,
            float* __restrict__ S1, float* __restrict__ S2)
{
    __shared__ float ml[NPGc][32];
    __shared__ float s1sh[4][32], s2sh[4][32];
    const int cc = blockIdx.x, g = blockIdx.y;
    const int tid = threadIdx.x, lane = tid & 63, w = tid >> 6;
    const int c2 = lane & 31, p = lane >> 5;
    const int nbase = g * NPGc;
    const int ch0 = cc * 32;

    #pragma unroll
    for (int i = 0; i < 16; ++i) {
        int flat = i * 256 + tid;
        if (flat < NPGc * 8) {
            int row = flat >> 3, q = flat & 7;
            *(float4*)&ml[row][q * 4] =
                *(const float4*)&m[((size_t)(nbase + row)) * HH + ch0 + q * 4];
        }
    }
    __syncthreads();

    const float bb = bias[ch0 + c2];
    float s1 = 0.f, s2 = 0.f;
    const int n0w = w * 125, n1w = n0w + 125;
    for (int n0 = n0w; n0 < n1w; n0 += 2) {
        int myn = n0 + p;
        bool valid = myn < n1w;
        int nn = valid ? myn : n0;
        int b3 = (nbase + nn) * 3;
        int a0 = fsrc[b3 + 0] - nbase;
        int a1 = fsrc[b3 + 1] - nbase;
        int a2 = fsrc[b3 + 2] - nbase;
        float outv = 0.25f * (ml[nn][c2] + ml[a0][c2] + ml[a1][c2] + ml[a2][c2]) + bb;
        if (valid) {
            out[((size_t)(nbase + nn)) * HH + ch0 + c2] = outv;
            s1 += outv; s2 += outv * outv;
        }
    }
    s1 += __shfl_xor(s1, 32);
    s2 += __shfl_xor(s2, 32);
    if (p == 0) { s1sh[w][c2] = s1; s2sh[w][c2] = s2; }
    __syncthreads();
    if (tid < 32) {
        float a = s1sh[0][tid] + s1sh[1][tid] + s1sh[2][tid] + s1sh[3][tid];
        float b = s2sh[0][tid] + s2sh[1][tid] + s2sh[2][tid] + s2sh[3][tid];
        S1[g * HH + ch0 + tid] = a;
        S2[g * HH + ch0 + tid] = b;
    }
}

// ---------------------------------------------------------------------------
// GraphNorm apply + leaky relu
// ---------------------------------------------------------------------------
__global__ __launch_bounds__(256)
void norm_apply(float* __restrict__ x, const float* __restrict__ S1, const float* __restrict__ S2,
                const float* __restrict__ w, const float* __restrict__ b,
                const float* __restrict__ ms)
{
    int n = blockIdx.x, c = threadIdx.x;
    int g = n / NPGc;
    size_t o = (size_t)n * HH + c;
    float v = x[o];
    float mean = S1[g * HH + c] / (float)NPGc;
    float mm = mean * ms[c];
    float var = S2[g * HH + c] / (float)NPGc - 2.f * mm * mean + mm * mm;
    float outv = w[c] * (v - mm) * rsqrtf(var + 1e-5f) + b[c];
    x[o] = outv > 0.f ? outv : 0.01f * outv;
}

// ---------------------------------------------------------------------------
// Pool: gf[g] = (sum X0 + 2*sum X1) / 500   (all_x[-1]==all_x[1] quirk)
// ---------------------------------------------------------------------------
__global__ __launch_bounds__(256)
void pool_kernel(const float* __restrict__ X0, const float* __restrict__ X1,
                 float* __restrict__ out)
{
    int g = blockIdx.x, c = threadIdx.x;
    float s0 = 0.f, s1 = 0.f;
    for (int r = 0; r < NPGc; ++r) {
        size_t o = ((size_t)(g * NPGc + r)) * HH + c;
        s0 += X0[o];
        s1 += X1[o];
    }
    out[g * HH + c] = (s0 + 2.f * s1) / (float)NPGc;
}

__global__ void sentinel_kernel(float* out, int n)
{
    int i = blockIdx.x * 256 + threadIdx.x;
    if (i < n) out[i] = 12345.0f;
}

// ---------------------------------------------------------------------------
extern "C" void kernel_launch(void* const* d_in, const int* in_sizes, int n_in,
                              void* d_out, int out_size, void* d_ws, size_t ws_size,
                              hipStream_t stream)
{
    const float* x       = (const float*)d_in[0];
    const int* edge_idx  = (const int*)d_in[1];
    const float* emb_W   = (const float*)d_in[3];
    const float* emb_b   = (const float*)d_in[4];
    const float* conv_W  = (const float*)d_in[5];
    const float* conv_b  = (const float*)d_in[6];
    const float* fconv_W = (const float*)d_in[7];
    const float* fconv_b = (const float*)d_in[8];
    const float* norm_w  = (const float*)d_in[9];
    const float* norm_b  = (const float*)d_in[10];
    const float* norm_ms = (const float*)d_in[11];
    const float* fnorm_w = (const float*)d_in[12];
    const float* fnorm_b = (const float*)d_in[13];
    const float* fnorm_ms= (const float*)d_in[14];
    const float* gate_W  = (const float*)d_in[15];
    const float* gate_b  = (const float*)d_in[16];

    const int E = in_sizes[1] / 2;
    const int* esrc = edge_idx;
    const int* edst = edge_idx + E;

    const size_t NHf = (size_t)NN * HH;           // 12.8M elements
    char* p = (char*)d_ws;
    auto alloc = [&](size_t bytes) { char* r = p; p += (bytes + 255) & ~(size_t)255; return r; };
    float* B0 = (float*)alloc(NHf * 4);
    float* B1 = (float*)alloc(NHf * 4);
    float* B2 = (float*)alloc(NHf * 4);
    float* B3 = (float*)alloc(NHf * 4);
    ushort* xnh = (ushort*)B2;          // 25.6MB overlay, dead once layers start
    ushort* xnl = xnh + NHf;            // 25.6MB (rest of B2)
    int* sorted_src = (int*)alloc((size_t)E * 4);
    int* row_ptr    = (int*)alloc((size_t)NN * 4);
    int* deg_cnt    = (int*)alloc((size_t)NN * 4);
    int* cursor     = (int*)alloc((size_t)NN * 4);
    float* dinv     = (float*)alloc((size_t)NN * 4);
    int* fsrc       = (int*)alloc((size_t)NN * 3 * 4);
    float* S1       = (float*)alloc((size_t)GG * HH * 4);
    float* S2       = (float*)alloc((size_t)GG * HH * 4);
    int* bsum       = (int*)alloc(1024);
    ushort* wts     = (ushort*)alloc((size_t)425984 * 2);  // all W^T bf16
    float* cval     = (float*)alloc((size_t)NN * 12 * 4);  // topk candidates
    int*   cidx     = (int*)alloc((size_t)NN * 12 * 4);
    size_t needed = (size_t)(p - (char*)d_ws);
    if (ws_size < needed) {
        sentinel_kernel<<<(out_size + 255) / 256, 256, 0, stream>>>((float*)d_out, out_size);
        return;
    }
    ushort* embWt   = wts;                    // [256][128]
    ushort* convWt0 = wts + 32768;            // [256][256]
    ushort* convWt1 = wts + 32768 + 65536;
    ushort* fconvWt0 = wts + 163840;
    ushort* fconvWt1 = wts + 163840 + 65536;
    ushort* gateWt  = wts + 294912;           // [256][512]

    const int nScanB = (NN + 255) / 256;  // 196

    hipMemsetAsync(deg_cnt, 0, (size_t)NN * 4, stream);
    hipMemsetAsync(cursor, 0, (size_t)NN * 4, stream);

    // 0. weight transpose+cvt
    wcvt<<<(32768 + 255) / 256, 256, 0, stream>>>(emb_W, embWt, IND, HH);
    wcvt<<<(65536 + 255) / 256, 256, 0, stream>>>(conv_W, convWt0, HH, HH);
    wcvt<<<(65536 + 255) / 256, 256, 0, stream>>>(conv_W + 65536, convWt1, HH, HH);
    wcvt<<<(65536 + 255) / 256, 256, 0, stream>>>(fconv_W, fconvWt0, HH, HH);
    wcvt<<<(65536 + 255) / 256, 256, 0, stream>>>(fconv_W + 65536, fconvWt1, HH, HH);
    wcvt<<<(131072 + 255) / 256, 256, 0, stream>>>(gate_W, gateWt, 2 * HH, HH);

    // 1. embedding: h0 = x @ emb_W + emb_b -> B0
    dim3 ggrid((NN + 127) / 128, 2);
    gemm_mfma<<<ggrid, 256, 0, stream>>>(x, nullptr, embWt, emb_b, B0, NN, IND, IND, 0,
                                         nullptr, nullptr, nullptr);

    // 2. CSR of edge_index by dst
    hist_kernel<<<(E + 255) / 256, 256, 0, stream>>>(edst, deg_cnt, E);
    scan1_kernel<<<nScanB, 256, 0, stream>>>(deg_cnt, row_ptr, bsum, NN);
    scan2_kernel<<<1, 256, 0, stream>>>(bsum, nScanB);
    scan3_kernel<<<nScanB, 256, 0, stream>>>(row_ptr, bsum, NN);
    fill_kernel<<<(E + 255) / 256, 256, 0, stream>>>(esrc, edst, row_ptr, cursor, sorted_src, E);
    dinv_kernel<<<(NN + 255) / 256, 256, 0, stream>>>(deg_cnt, dinv, NN);

    // 3. knn graph from h0 (hi/lo split, tiled sim + candidate merge)
    row_norm_hl<<<NN, 256, 0, stream>>>(B0, xnh, xnl);
    simtopk_tile<<<1664, 256, 0, stream>>>(xnh, xnl, cval, cidx);
    cand_merge<<<(NN + 255) / 256, 256, 0, stream>>>(cval, cidx, fsrc);

    // 4. layers
    float* h  = B0;
    float* mb = B1;
    dim3 sgrid8(8, GG);
    for (int i = 0; i < 2; ++i) {
        const ushort* Wc = (i == 0) ? convWt0 : convWt1;
        const ushort* Wf = (i == 0) ? fconvWt0 : fconvWt1;
        const float* bc  = conv_b  + (size_t)i * HH;
        const float* bf  = fconv_b + (size_t)i * HH;
        // h-road conv
        gemm_mfma<<<ggrid, 256, 0, stream>>>(h, nullptr, Wc, nullptr, mb, NN, HH, HH, 0,
                                             nullptr, nullptr, nullptr);
        gcn32<<<sgrid8, 256, 0, stream>>>(mb, row_ptr, deg_cnt, sorted_src, dinv, bc,
                                          B2, S1, S2);
        norm_apply<<<NN, 256, 0, stream>>>(B2, S1, S2, norm_w + i * HH, norm_b + i * HH,
                                           norm_ms + i * HH);
        // f-road conv (knn graph)
        gemm_mfma<<<ggrid, 256, 0, stream>>>(B2, nullptr, Wf, nullptr, mb, NN, HH, HH, 0,
                                             nullptr, nullptr, nullptr);
        fgcn32<<<sgrid8, 256, 0, stream>>>(mb, fsrc, bf, B3, S1, S2);
        norm_apply<<<NN, 256, 0, stream>>>(B3, S1, S2, fnorm_w + i * HH, fnorm_b + i * HH,
                                           fnorm_ms + i * HH);
        // gate + combine
        gemm_mfma<<<ggrid, 256, 0, stream>>>(B2, B3, gateWt, gate_b, mb, NN, 2 * HH, HH, 1,
                                             B2, B3, h);
        float* t = h; h = mb; mb = t;
    }
    // h = all_x[1], mb = all_x[0]
    pool_kernel<<<GG, 256, 0, stream>>>(mb, h, (float*)d_out);
}

// Round 6
// 1377.143 us; speedup vs baseline: 1.2117x; 1.2117x over previous
//
#include <hip/hip_runtime.h>
#include <math.h>

#define NN 50000      // nodes
#define GG 100        // graphs
#define NPGc 500      // nodes per graph
#define HH 256        // hidden
#define IND 128       // input dim

typedef __attribute__((ext_vector_type(8))) short short8v;  // 8 bf16
typedef __attribute__((ext_vector_type(4))) float f32x4;

__device__ __forceinline__ ushort f2bf(float f) {
    union { float f; unsigned u; } v; v.f = f;
    unsigned r = (v.u + 0x7fffu + ((v.u >> 16) & 1u)) >> 16;  // RNE
    return (ushort)r;
}
__device__ __forceinline__ float bf2f(ushort h) {
    union { unsigned u; float f; } v; v.u = ((unsigned)h) << 16;
    return v.f;
}

// LDS ushort-index swizzle: XOR 16B-granule bits with row&7 (T2, bank-conflict fix)
__device__ __forceinline__ int swz(int row, int kidx) { return kidx ^ ((row & 7) << 3); }

// ---------------------------------------------------------------------------
// Weight transpose+convert: src [K][N] f32 -> dst [N][K] bf16
// ---------------------------------------------------------------------------
__global__ void wcvt(const float* __restrict__ src, ushort* __restrict__ dst, int K, int N)
{
    int i = blockIdx.x * 256 + threadIdx.x;
    if (i < K * N) {
        int n = i / K, k = i % K;
        dst[i] = f2bf(src[(size_t)k * N + n]);
    }
}

// ---------------------------------------------------------------------------
// bf16 MFMA GEMM: C[M x 256] = A[M x K](f32, cvt on stage) @ Wt[N=256][K](bf16)
// tile 128x128, BK=64, 4 waves each 64x64. LDS XOR-swizzled.
// mode 0: C = acc (+bias). mode 1: gate epilogue.
// ---------------------------------------------------------------------------
__global__ __launch_bounds__(256)
void gemm_mfma(const float* __restrict__ A, const float* __restrict__ A2,
               const ushort* __restrict__ Wt, const float* __restrict__ bias,
               float* __restrict__ C, int M, int K, int lda, int mode,
               const float* __restrict__ hn, const float* __restrict__ fn,
               const float* __restrict__ prev)
{
    __shared__ ushort As[128][64];
    __shared__ ushort Bs[128][64];
    const int tid = threadIdx.x;
    const int lane = tid & 63;
    const int w = tid >> 6;
    const int wr = (w >> 1) * 64, wc = (w & 1) * 64;
    const int row0 = blockIdx.x * 128, col0 = blockIdx.y * 128;
    const int lr = lane & 15, lk = (lane >> 4) * 8;
    f32x4 acc[4][4] = {};

    for (int k0 = 0; k0 < K; k0 += 64) {
        __syncthreads();
        #pragma unroll
        for (int it = 0; it < 4; ++it) {           // stage A: 128x64, f32->bf16
            int c = it * 256 + tid;
            int row = c >> 3, col = (c & 7) * 8;
            int gr = row0 + row; if (gr > M - 1) gr = M - 1;
            const float* Ap = A; int kk = k0 + col;
            if (A2 != nullptr && kk >= 256) { Ap = A2; kk -= 256; }
            const float* s = &Ap[(size_t)gr * lda + kk];
            float4 v0 = *(const float4*)s;
            float4 v1 = *(const float4*)(s + 4);
            union { ushort u[8]; int4 q; } pk;
            pk.u[0] = f2bf(v0.x); pk.u[1] = f2bf(v0.y); pk.u[2] = f2bf(v0.z); pk.u[3] = f2bf(v0.w);
            pk.u[4] = f2bf(v1.x); pk.u[5] = f2bf(v1.y); pk.u[6] = f2bf(v1.z); pk.u[7] = f2bf(v1.w);
            *(int4*)&As[row][swz(row, col)] = pk.q;
        }
        #pragma unroll
        for (int it = 0; it < 4; ++it) {           // stage B: Wt rows col0..+127
            int c = it * 256 + tid;
            int n = c >> 3, k = (c & 7) * 8;
            *(int4*)&Bs[n][swz(n, k)] = *(const int4*)&Wt[(size_t)(col0 + n) * K + k0 + k];
        }
        __syncthreads();
        #pragma unroll
        for (int ks = 0; ks < 2; ++ks) {
            short8v av[4], bv[4];
            #pragma unroll
            for (int m = 0; m < 4; ++m) {
                int rr = wr + m * 16 + lr;
                av[m] = *(const short8v*)&As[rr][swz(rr, ks * 32 + lk)];
            }
            #pragma unroll
            for (int n = 0; n < 4; ++n) {
                int rr = wc + n * 16 + lr;
                bv[n] = *(const short8v*)&Bs[rr][swz(rr, ks * 32 + lk)];
            }
            #pragma unroll
            for (int m = 0; m < 4; ++m)
                #pragma unroll
                for (int n = 0; n < 4; ++n)
                    acc[m][n] = __builtin_amdgcn_mfma_f32_16x16x32_bf16(av[m], bv[n], acc[m][n], 0, 0, 0);
        }
    }
    const int fr = (lane >> 4) * 4;
    if (mode == 0) {
        #pragma unroll
        for (int n = 0; n < 4; ++n) {
            int col = col0 + wc + n * 16 + lr;
            float bb = bias ? bias[col] : 0.f;
            #pragma unroll
            for (int m = 0; m < 4; ++m) {
                int rbase = row0 + wr + m * 16 + fr;
                #pragma unroll
                for (int r = 0; r < 4; ++r) {
                    int row = rbase + r;
                    if (row < M) C[(size_t)row * HH + col] = acc[m][n][r] + bb;
                }
            }
        }
    } else {
        #pragma unroll
        for (int n = 0; n < 4; ++n) {
            int col = col0 + wc + n * 16 + lr;
            float gb = bias[col];
            #pragma unroll
            for (int m = 0; m < 4; ++m) {
                int rbase = row0 + wr + m * 16 + fr;
                #pragma unroll
                for (int r = 0; r < 4; ++r) {
                    int row = rbase + r;
                    if (row < M) {
                        size_t o = (size_t)row * HH + col;
                        float z = acc[m][n][r] + gb;
                        float s = 1.f / (1.f + expf(-z));
                        C[o] = s * hn[o] + (1.f - s) * fn[o] + prev[o];
                    }
                }
            }
        }
    }
}

// ---------------------------------------------------------------------------
// Row L2-normalize, emit bf16 hi/lo split
// ---------------------------------------------------------------------------
__global__ __launch_bounds__(256)
void row_norm_hl(const float* __restrict__ h, ushort* __restrict__ xh, ushort* __restrict__ xl)
{
    int n = blockIdx.x, c = threadIdx.x;
    float v = h[(size_t)n * HH + c];
    __shared__ float red[256];
    red[c] = v * v;
    __syncthreads();
    for (int s = 128; s > 0; s >>= 1) {
        if (c < s) red[c] += red[c + s];
        __syncthreads();
    }
    float norm = sqrtf(red[0]);
    float xn = v / (norm + 1e-12f);
    ushort hi = f2bf(xn);
    xh[(size_t)n * HH + c] = hi;
    xl[(size_t)n * HH + c] = f2bf(xn - bf2f(hi));
}

// ---------------------------------------------------------------------------
// top-3 helpers (exact top_k tie-breaking: value desc, index asc)
// ---------------------------------------------------------------------------
__device__ __forceinline__ bool tk_better(float va, int ia, float vb, int ib)
{
    return (va > vb) || (va == vb && ia < ib);
}

__device__ __forceinline__ void ins3(float v, int i,
                                     float& a0, int& b0, float& a1, int& b1,
                                     float& a2, int& b2)
{
    if (tk_better(v, i, a0, b0))      { a2 = a1; b2 = b1; a1 = a0; b1 = b0; a0 = v; b0 = i; }
    else if (tk_better(v, i, a1, b1)) { a2 = a1; b2 = b1; a1 = v;  b1 = i; }
    else if (tk_better(v, i, a2, b2)) { a2 = v;  b2 = i; }
}

__device__ __forceinline__ void merge3(float& v0, float& v1, float& v2,
                                       int& i0, int& i1, int& i2, int off)
{
    float w0 = __shfl_xor(v0, off), w1 = __shfl_xor(v1, off), w2 = __shfl_xor(v2, off);
    int   j0 = __shfl_xor(i0, off), j1 = __shfl_xor(i1, off), j2 = __shfl_xor(i2, off);
    float avv[3] = { v0, v1, v2 }, bvv[3] = { w0, w1, w2 };
    int   aii[3] = { i0, i1, i2 }, bii[3] = { j0, j1, j2 };
    float rv[3]; int ri[3];
    int p = 0, q = 0;
    #pragma unroll
    for (int t = 0; t < 3; ++t) {
        bool takeA = tk_better(avv[p], aii[p], bvv[q], bii[q]);
        rv[t] = takeA ? avv[p] : bvv[q];
        ri[t] = takeA ? aii[p] : bii[q];
        if (takeA) ++p; else ++q;
    }
    v0 = rv[0]; v1 = rv[1]; v2 = rv[2];
    i0 = ri[0]; i1 = ri[1]; i2 = ri[2];
}

// ---------------------------------------------------------------------------
// Fused per-graph cosine knn: LDS-staged MFMA sim (hi/lo split) + in-register
// top-3. Block = 128 rows of one graph; 4 col-tiles of 128; BK=64.
// XCD-swizzled 1D grid: all 4 row-blocks of a graph share one XCD residue
// (blocks dispatch round-robin across 8 XCDs) so the graph's 1MB hi/lo panel
// is fetched from HBM once and re-read from that XCD's L2 by the other 3.
// ---------------------------------------------------------------------------
__global__ __launch_bounds__(256, 2)
void simtopk(const ushort* __restrict__ xnh, const ushort* __restrict__ xnl,
             int* __restrict__ fsrc)
{
    __shared__ ushort Ash[128][64], Asl[128][64], Bsh[128][64], Bsl[128][64];  // 64KB
    const int bid = blockIdx.x;
    const int xcd = bid & 7;
    const int rb  = (bid >> 3) & 3;
    const int g   = (bid >> 5) * 8 + xcd;
    if (g >= GG) return;
    const int row0 = rb * 128;
    const int tid = threadIdx.x;
    const int lane = tid & 63;
    const int w = tid >> 6;
    const int wrow = w * 32;            // wave owns 32 rows (2 m-tiles)
    const int lr = lane & 15;
    const int hi4 = lane >> 4;
    const int lk = hi4 * 8;
    const size_t base = (size_t)g * NPGc * HH;

    // running top-3 per (m, r): rows wrow + m*16 + hi4*4 + r
    float tv0[2][4], tv1[2][4], tv2[2][4];
    int   ti0[2][4], ti1[2][4], ti2[2][4];
    #pragma unroll
    for (int m = 0; m < 2; ++m)
        #pragma unroll
        for (int r = 0; r < 4; ++r) {
            tv0[m][r] = tv1[m][r] = tv2[m][r] = -2.f;
            ti0[m][r] = ti1[m][r] = ti2[m][r] = 0x7fffffff;
        }

    for (int ct = 0; ct < 4; ++ct) {
        const int col0 = ct * 128;
        f32x4 acc[2][8] = {};
        for (int k0 = 0; k0 < HH; k0 += 64) {
            __syncthreads();
            #pragma unroll
            for (int it = 0; it < 4; ++it) {       // stage A rows (hi+lo)
                int c = it * 256 + tid;
                int rr = c >> 3, kc = (c & 7) * 8;
                int grow = row0 + rr; if (grow > NPGc - 1) grow = NPGc - 1;
                const size_t o = base + (size_t)grow * HH + k0 + kc;
                *(int4*)&Ash[rr][swz(rr, kc)] = *(const int4*)(xnh + o);
                *(int4*)&Asl[rr][swz(rr, kc)] = *(const int4*)(xnl + o);
            }
            #pragma unroll
            for (int it = 0; it < 4; ++it) {       // stage B cols (hi+lo)
                int c = it * 256 + tid;
                int rr = c >> 3, kc = (c & 7) * 8;
                int gcol = col0 + rr; if (gcol > NPGc - 1) gcol = NPGc - 1;
                const size_t o = base + (size_t)gcol * HH + k0 + kc;
                *(int4*)&Bsh[rr][swz(rr, kc)] = *(const int4*)(xnh + o);
                *(int4*)&Bsl[rr][swz(rr, kc)] = *(const int4*)(xnl + o);
            }
            __syncthreads();
            #pragma unroll
            for (int ks = 0; ks < 2; ++ks) {
                short8v ah[2], al[2], bh[8], bl[8];
                #pragma unroll
                for (int m = 0; m < 2; ++m) {
                    int rr = wrow + m * 16 + lr;
                    ah[m] = *(const short8v*)&Ash[rr][swz(rr, ks * 32 + lk)];
                    al[m] = *(const short8v*)&Asl[rr][swz(rr, ks * 32 + lk)];
                }
                #pragma unroll
                for (int n = 0; n < 8; ++n) {
                    int rr = n * 16 + lr;
                    bh[n] = *(const short8v*)&Bsh[rr][swz(rr, ks * 32 + lk)];
                    bl[n] = *(const short8v*)&Bsl[rr][swz(rr, ks * 32 + lk)];
                }
                #pragma unroll
                for (int m = 0; m < 2; ++m)
                    #pragma unroll
                    for (int n = 0; n < 8; ++n) {
                        acc[m][n] = __builtin_amdgcn_mfma_f32_16x16x32_bf16(ah[m], bh[n], acc[m][n], 0, 0, 0);
                        acc[m][n] = __builtin_amdgcn_mfma_f32_16x16x32_bf16(ah[m], bl[n], acc[m][n], 0, 0, 0);
                        acc[m][n] = __builtin_amdgcn_mfma_f32_16x16x32_bf16(al[m], bh[n], acc[m][n], 0, 0, 0);
                    }
            }
        }
        // fold this col-tile into running top-3 (lane's col = col0 + n*16 + lr)
        #pragma unroll
        for (int m = 0; m < 2; ++m)
            #pragma unroll
            for (int n = 0; n < 8; ++n) {
                int col = col0 + n * 16 + lr;
                if (col < NPGc) {
                    #pragma unroll
                    for (int r = 0; r < 4; ++r)
                        ins3(acc[m][n][r], col,
                             tv0[m][r], ti0[m][r], tv1[m][r], ti1[m][r], tv2[m][r], ti2[m][r]);
                }
            }
    }

    // merge across the 16 lanes sharing each row-quad (xor 1,2,4,8)
    #pragma unroll
    for (int m = 0; m < 2; ++m)
        #pragma unroll
        for (int r = 0; r < 4; ++r) {
            #pragma unroll
            for (int off = 1; off <= 8; off <<= 1)
                merge3(tv0[m][r], tv1[m][r], tv2[m][r],
                       ti0[m][r], ti1[m][r], ti2[m][r], off);
        }

    if (lr == 0) {
        #pragma unroll
        for (int m = 0; m < 2; ++m)
            #pragma unroll
            for (int r = 0; r < 4; ++r) {
                int row = row0 + wrow + m * 16 + hi4 * 4 + r;
                if (row < NPGc) {
                    int rg = g * NPGc + row;
                    fsrc[rg * 3 + 0] = g * NPGc + ti0[m][r];
                    fsrc[rg * 3 + 1] = g * NPGc + ti1[m][r];
                    fsrc[rg * 3 + 2] = g * NPGc + ti2[m][r];
                }
            }
    }
}

// ---------------------------------------------------------------------------
// CSR build
// ---------------------------------------------------------------------------
__global__ void hist_kernel(const int* __restrict__ dst, int* __restrict__ cnt, int nE)
{
    int e = blockIdx.x * 256 + threadIdx.x;
    if (e < nE) atomicAdd(&cnt[dst[e]], 1);
}

__global__ void scan1_kernel(const int* __restrict__ in, int* __restrict__ out,
                             int* __restrict__ bsum, int n)
{
    __shared__ int sh[256];
    int t = threadIdx.x;
    int i = blockIdx.x * 256 + t;
    int v = (i < n) ? in[i] : 0;
    sh[t] = v;
    __syncthreads();
    for (int s = 1; s < 256; s <<= 1) {
        int tv = (t >= s) ? sh[t - s] : 0;
        __syncthreads();
        sh[t] += tv;
        __syncthreads();
    }
    if (i < n) out[i] = sh[t] - v;  // exclusive
    if (t == 255) bsum[blockIdx.x] = sh[255];
}

__global__ void scan2_kernel(int* __restrict__ bsum, int nb)
{
    __shared__ int sh[256];
    int t = threadIdx.x;
    int v = (t < nb) ? bsum[t] : 0;
    sh[t] = v;
    __syncthreads();
    for (int s = 1; s < 256; s <<= 1) {
        int tv = (t >= s) ? sh[t - s] : 0;
        __syncthreads();
        sh[t] += tv;
        __syncthreads();
    }
    if (t < nb) bsum[t] = sh[t] - v;  // exclusive block offsets
}

__global__ void scan3_kernel(int* __restrict__ out, const int* __restrict__ bsum, int n)
{
    int i = blockIdx.x * 256 + threadIdx.x;
    if (i < n) out[i] += bsum[blockIdx.x];
}

__global__ void fill_kernel(const int* __restrict__ src, const int* __restrict__ dst,
                            const int* __restrict__ row_ptr, int* __restrict__ cursor,
                            int* __restrict__ sorted_src, int nE)
{
    int e = blockIdx.x * 256 + threadIdx.x;
    if (e < nE) {
        int d = dst[e];
        int pos = row_ptr[d] + atomicAdd(&cursor[d], 1);
        sorted_src[pos] = src[e];
    }
}

__global__ void dinv_kernel(const int* __restrict__ cnt, float* __restrict__ dinv, int n)
{
    int i = blockIdx.x * 256 + threadIdx.x;
    if (i < n) dinv[i] = rsqrtf((float)cnt[i] + 1.0f);
}

// ---------------------------------------------------------------------------
// GCN gather
// ---------------------------------------------------------------------------
__global__ __launch_bounds__(256)
void gcn_gather(const float* __restrict__ m, const int* __restrict__ row_ptr,
                const int* __restrict__ cnt, const int* __restrict__ srcs,
                const float* __restrict__ dinv, const float* __restrict__ bias,
                float* __restrict__ out)
{
    int n = blockIdx.x, c = threadIdx.x;
    float dn = dinv[n];
    float acc = m[(size_t)n * HH + c] * dn;
    int s0 = row_ptr[n], e0 = s0 + cnt[n];
    for (int e = s0; e < e0; ++e) {
        int s = srcs[e];
        acc += m[(size_t)s * HH + c] * dinv[s];
    }
    out[(size_t)n * HH + c] = acc * dn + bias[c];
}

// knn-graph conv: all degrees are K+1=4 -> coef = 0.25 everywhere
__global__ __launch_bounds__(256)
void fgcn_gather(const float* __restrict__ m, const int* __restrict__ fsrc,
                 const float* __restrict__ bias, float* __restrict__ out)
{
    int n = blockIdx.x, c = threadIdx.x;
    int s0 = fsrc[n * 3], s1 = fsrc[n * 3 + 1], s2 = fsrc[n * 3 + 2];
    float acc = m[(size_t)n * HH + c] + m[(size_t)s0 * HH + c]
              + m[(size_t)s1 * HH + c] + m[(size_t)s2 * HH + c];
    out[(size_t)n * HH + c] = 0.25f * acc + bias[c];
}

// ---------------------------------------------------------------------------
// GraphNorm
// ---------------------------------------------------------------------------
__global__ __launch_bounds__(256)
void norm_stats(const float* __restrict__ x, float* __restrict__ S1, float* __restrict__ S2)
{
    int g = blockIdx.x, chunk = blockIdx.y, c = threadIdx.x;
    int r0 = chunk * 63, r1 = min(r0 + 63, NPGc);
    float s1 = 0.f, s2 = 0.f;
    for (int r = r0; r < r1; ++r) {
        float v = x[((size_t)(g * NPGc + r)) * HH + c];
        s1 += v; s2 += v * v;
    }
    atomicAdd(&S1[g * HH + c], s1);
    atomicAdd(&S2[g * HH + c], s2);
}

__global__ __launch_bounds__(256)
void norm_apply(float* __restrict__ x, const float* __restrict__ S1, const float* __restrict__ S2,
                const float* __restrict__ w, const float* __restrict__ b,
                const float* __restrict__ ms)
{
    int n = blockIdx.x, c = threadIdx.x;
    int g = n / NPGc;
    size_t o = (size_t)n * HH + c;
    float v = x[o];
    float mean = S1[g * HH + c] / (float)NPGc;
    float mm = mean * ms[c];
    float var = S2[g * HH + c] / (float)NPGc - 2.f * mm * mean + mm * mm;
    float outv = w[c] * (v - mm) * rsqrtf(var + 1e-5f) + b[c];
    x[o] = outv > 0.f ? outv : 0.01f * outv;
}

// ---------------------------------------------------------------------------
// Pool: gf[g] = (sum X0 + 2*sum X1) / 500   (all_x[-1]==all_x[1] quirk)
// ---------------------------------------------------------------------------
__global__ __launch_bounds__(256)
void pool_kernel(const float* __restrict__ X0, const float* __restrict__ X1,
                 float* __restrict__ out)
{
    int g = blockIdx.x, c = threadIdx.x;
    float s0 = 0.f, s1 = 0.f;
    for (int r = 0; r < NPGc; ++r) {
        size_t o = ((size_t)(g * NPGc + r)) * HH + c;
        s0 += X0[o];
        s1 += X1[o];
    }
    out[g * HH + c] = (s0 + 2.f * s1) / (float)NPGc;
}

__global__ void sentinel_kernel(float* out, int n)
{
    int i = blockIdx.x * 256 + threadIdx.x;
    if (i < n) out[i] = 12345.0f;
}

// ---------------------------------------------------------------------------
extern "C" void kernel_launch(void* const* d_in, const int* in_sizes, int n_in,
                              void* d_out, int out_size, void* d_ws, size_t ws_size,
                              hipStream_t stream)
{
    const float* x       = (const float*)d_in[0];
    const int* edge_idx  = (const int*)d_in[1];
    const float* emb_W   = (const float*)d_in[3];
    const float* emb_b   = (const float*)d_in[4];
    const float* conv_W  = (const float*)d_in[5];
    const float* conv_b  = (const float*)d_in[6];
    const float* fconv_W = (const float*)d_in[7];
    const float* fconv_b = (const float*)d_in[8];
    const float* norm_w  = (const float*)d_in[9];
    const float* norm_b  = (const float*)d_in[10];
    const float* norm_ms = (const float*)d_in[11];
    const float* fnorm_w = (const float*)d_in[12];
    const float* fnorm_b = (const float*)d_in[13];
    const float* fnorm_ms= (const float*)d_in[14];
    const float* gate_W  = (const float*)d_in[15];
    const float* gate_b  = (const float*)d_in[16];

    const int E = in_sizes[1] / 2;
    const int* esrc = edge_idx;
    const int* edst = edge_idx + E;

    const size_t NHf = (size_t)NN * HH;           // 12.8M elements
    char* p = (char*)d_ws;
    auto alloc = [&](size_t bytes) { char* r = p; p += (bytes + 255) & ~(size_t)255; return r; };
    float* B0 = (float*)alloc(NHf * 4);
    float* B1 = (float*)alloc(NHf * 4);
    float* B2 = (float*)alloc(NHf * 4);
    float* B3 = (float*)alloc(NHf * 4);
    ushort* xnh = (ushort*)B2;          // 25.6MB overlay, dead once layers start
    ushort* xnl = xnh + NHf;            // 25.6MB (rest of B2)
    int* sorted_src = (int*)alloc((size_t)E * 4);
    int* row_ptr    = (int*)alloc((size_t)NN * 4);
    int* deg_cnt    = (int*)alloc((size_t)NN * 4);
    int* cursor     = (int*)alloc((size_t)NN * 4);
    float* dinv     = (float*)alloc((size_t)NN * 4);
    int* fsrc       = (int*)alloc((size_t)NN * 3 * 4);
    float* S1       = (float*)alloc((size_t)GG * HH * 4);
    float* S2       = (float*)alloc((size_t)GG * HH * 4);
    int* bsum       = (int*)alloc(1024);
    ushort* wts     = (ushort*)alloc((size_t)425984 * 2);  // all W^T bf16
    size_t needed = (size_t)(p - (char*)d_ws);
    if (ws_size < needed) {
        sentinel_kernel<<<(out_size + 255) / 256, 256, 0, stream>>>((float*)d_out, out_size);
        return;
    }
    ushort* embWt   = wts;                    // [256][128]
    ushort* convWt0 = wts + 32768;            // [256][256]
    ushort* convWt1 = wts + 32768 + 65536;
    ushort* fconvWt0 = wts + 163840;
    ushort* fconvWt1 = wts + 163840 + 65536;
    ushort* gateWt  = wts + 294912;           // [256][512]

    const int nScanB = (NN + 255) / 256;  // 196

    hipMemsetAsync(deg_cnt, 0, (size_t)NN * 4, stream);
    hipMemsetAsync(cursor, 0, (size_t)NN * 4, stream);

    // 0. weight transpose+cvt
    wcvt<<<(32768 + 255) / 256, 256, 0, stream>>>(emb_W, embWt, IND, HH);
    wcvt<<<(65536 + 255) / 256, 256, 0, stream>>>(conv_W, convWt0, HH, HH);
    wcvt<<<(65536 + 255) / 256, 256, 0, stream>>>(conv_W + 65536, convWt1, HH, HH);
    wcvt<<<(65536 + 255) / 256, 256, 0, stream>>>(fconv_W, fconvWt0, HH, HH);
    wcvt<<<(65536 + 255) / 256, 256, 0, stream>>>(fconv_W + 65536, fconvWt1, HH, HH);
    wcvt<<<(131072 + 255) / 256, 256, 0, stream>>>(gate_W, gateWt, 2 * HH, HH);

    // 1. embedding: h0 = x @ emb_W + emb_b -> B0
    dim3 ggrid((NN + 127) / 128, 2);
    gemm_mfma<<<ggrid, 256, 0, stream>>>(x, nullptr, embWt, emb_b, B0, NN, IND, IND, 0,
                                         nullptr, nullptr, nullptr);

    // 2. CSR of edge_index by dst
    hist_kernel<<<(E + 255) / 256, 256, 0, stream>>>(edst, deg_cnt, E);
    scan1_kernel<<<nScanB, 256, 0, stream>>>(deg_cnt, row_ptr, bsum, NN);
    scan2_kernel<<<1, 256, 0, stream>>>(bsum, nScanB);
    scan3_kernel<<<nScanB, 256, 0, stream>>>(row_ptr, bsum, NN);
    fill_kernel<<<(E + 255) / 256, 256, 0, stream>>>(esrc, edst, row_ptr, cursor, sorted_src, E);
    dinv_kernel<<<(NN + 255) / 256, 256, 0, stream>>>(deg_cnt, dinv, NN);

    // 3. knn graph from h0 (hi/lo split, fused LDS-staged sim + in-reg topk)
    row_norm_hl<<<NN, 256, 0, stream>>>(B0, xnh, xnl);
    simtopk<<<416, 256, 0, stream>>>(xnh, xnl, fsrc);   // XCD-swizzled 1D grid

    // 4. layers
    float* h  = B0;
    float* mb = B1;
    dim3 ngrid(GG, 8);
    for (int i = 0; i < 2; ++i) {
        const ushort* Wc = (i == 0) ? convWt0 : convWt1;
        const ushort* Wf = (i == 0) ? fconvWt0 : fconvWt1;
        const float* bc  = conv_b  + (size_t)i * HH;
        const float* bf  = fconv_b + (size_t)i * HH;
        // h-road conv
        gemm_mfma<<<ggrid, 256, 0, stream>>>(h, nullptr, Wc, nullptr, mb, NN, HH, HH, 0,
                                             nullptr, nullptr, nullptr);
        gcn_gather<<<NN, 256, 0, stream>>>(mb, row_ptr, deg_cnt, sorted_src, dinv, bc, B2);
        hipMemsetAsync(S1, 0, (size_t)2 * GG * HH * 4, stream);
        norm_stats<<<ngrid, 256, 0, stream>>>(B2, S1, S2);
        norm_apply<<<NN, 256, 0, stream>>>(B2, S1, S2, norm_w + i * HH, norm_b + i * HH,
                                           norm_ms + i * HH);
        // f-road conv (knn graph)
        gemm_mfma<<<ggrid, 256, 0, stream>>>(B2, nullptr, Wf, nullptr, mb, NN, HH, HH, 0,
                                             nullptr, nullptr, nullptr);
        fgcn_gather<<<NN, 256, 0, stream>>>(mb, fsrc, bf, B3);
        hipMemsetAsync(S1, 0, (size_t)2 * GG * HH * 4, stream);
        norm_stats<<<ngrid, 256, 0, stream>>>(B3, S1, S2);
        norm_apply<<<NN, 256, 0, stream>>>(B3, S1, S2, fnorm_w + i * HH, fnorm_b + i * HH,
                                           fnorm_ms + i * HH);
        // gate + combine
        gemm_mfma<<<ggrid, 256, 0, stream>>>(B2, B3, gateWt, gate_b, mb, NN, 2 * HH, HH, 1,
                                             B2, B3, h);
        float* t = h; h = mb; mb = t;
    }
    // h = all_x[1], mb = all_x[0]
    pool_kernel<<<GG, 256, 0, stream>>>(mb, h, (float*)d_out);
}

// Round 7
// 1371.231 us; speedup vs baseline: 1.2169x; 1.0043x over previous
//
#include <hip/hip_runtime.h>
#include <math.h>

#define NN 50000      // nodes
#define GG 100        // graphs
#define NPGc 500      // nodes per graph
#define HH 256        // hidden
#define IND 128       // input dim

typedef __attribute__((ext_vector_type(8))) short short8v;  // 8 bf16
typedef __attribute__((ext_vector_type(4))) float f32x4;

__device__ __forceinline__ ushort f2bf(float f) {
    union { float f; unsigned u; } v; v.f = f;
    unsigned r = (v.u + 0x7fffu + ((v.u >> 16) & 1u)) >> 16;  // RNE
    return (ushort)r;
}
__device__ __forceinline__ float bf2f(ushort h) {
    union { unsigned u; float f; } v; v.u = ((unsigned)h) << 16;
    return v.f;
}

// LDS ushort-index swizzle: XOR 16B-granule bits with row&7 (T2, bank-conflict fix)
__device__ __forceinline__ int swz(int row, int kidx) { return kidx ^ ((row & 7) << 3); }

// ---------------------------------------------------------------------------
// Weight transpose+convert: src [K][N] f32 -> dst [N][K] bf16
// ---------------------------------------------------------------------------
__global__ void wcvt(const float* __restrict__ src, ushort* __restrict__ dst, int K, int N)
{
    int i = blockIdx.x * 256 + threadIdx.x;
    if (i < K * N) {
        int n = i / K, k = i % K;
        dst[i] = f2bf(src[(size_t)k * N + n]);
    }
}

// ---------------------------------------------------------------------------
// bf16 MFMA GEMM: C[M x 256] = A[M x K](f32, cvt on stage) @ Wt[N=256][K](bf16)
// tile 128x128, BK=64, 4 waves each 64x64. LDS XOR-swizzled.
// mode 0: C = acc (+bias). mode 1: gate epilogue.
// ---------------------------------------------------------------------------
__global__ __launch_bounds__(256)
void gemm_mfma(const float* __restrict__ A, const float* __restrict__ A2,
               const ushort* __restrict__ Wt, const float* __restrict__ bias,
               float* __restrict__ C, int M, int K, int lda, int mode,
               const float* __restrict__ hn, const float* __restrict__ fn,
               const float* __restrict__ prev)
{
    __shared__ ushort As[128][64];
    __shared__ ushort Bs[128][64];
    const int tid = threadIdx.x;
    const int lane = tid & 63;
    const int w = tid >> 6;
    const int wr = (w >> 1) * 64, wc = (w & 1) * 64;
    const int row0 = blockIdx.x * 128, col0 = blockIdx.y * 128;
    const int lr = lane & 15, lk = (lane >> 4) * 8;
    f32x4 acc[4][4] = {};

    for (int k0 = 0; k0 < K; k0 += 64) {
        __syncthreads();
        #pragma unroll
        for (int it = 0; it < 4; ++it) {           // stage A: 128x64, f32->bf16
            int c = it * 256 + tid;
            int row = c >> 3, col = (c & 7) * 8;
            int gr = row0 + row; if (gr > M - 1) gr = M - 1;
            const float* Ap = A; int kk = k0 + col;
            if (A2 != nullptr && kk >= 256) { Ap = A2; kk -= 256; }
            const float* s = &Ap[(size_t)gr * lda + kk];
            float4 v0 = *(const float4*)s;
            float4 v1 = *(const float4*)(s + 4);
            union { ushort u[8]; int4 q; } pk;
            pk.u[0] = f2bf(v0.x); pk.u[1] = f2bf(v0.y); pk.u[2] = f2bf(v0.z); pk.u[3] = f2bf(v0.w);
            pk.u[4] = f2bf(v1.x); pk.u[5] = f2bf(v1.y); pk.u[6] = f2bf(v1.z); pk.u[7] = f2bf(v1.w);
            *(int4*)&As[row][swz(row, col)] = pk.q;
        }
        #pragma unroll
        for (int it = 0; it < 4; ++it) {           // stage B: Wt rows col0..+127
            int c = it * 256 + tid;
            int n = c >> 3, k = (c & 7) * 8;
            *(int4*)&Bs[n][swz(n, k)] = *(const int4*)&Wt[(size_t)(col0 + n) * K + k0 + k];
        }
        __syncthreads();
        #pragma unroll
        for (int ks = 0; ks < 2; ++ks) {
            short8v av[4], bv[4];
            #pragma unroll
            for (int m = 0; m < 4; ++m) {
                int rr = wr + m * 16 + lr;
                av[m] = *(const short8v*)&As[rr][swz(rr, ks * 32 + lk)];
            }
            #pragma unroll
            for (int n = 0; n < 4; ++n) {
                int rr = wc + n * 16 + lr;
                bv[n] = *(const short8v*)&Bs[rr][swz(rr, ks * 32 + lk)];
            }
            #pragma unroll
            for (int m = 0; m < 4; ++m)
                #pragma unroll
                for (int n = 0; n < 4; ++n)
                    acc[m][n] = __builtin_amdgcn_mfma_f32_16x16x32_bf16(av[m], bv[n], acc[m][n], 0, 0, 0);
        }
    }
    const int fr = (lane >> 4) * 4;
    if (mode == 0) {
        #pragma unroll
        for (int n = 0; n < 4; ++n) {
            int col = col0 + wc + n * 16 + lr;
            float bb = bias ? bias[col] : 0.f;
            #pragma unroll
            for (int m = 0; m < 4; ++m) {
                int rbase = row0 + wr + m * 16 + fr;
                #pragma unroll
                for (int r = 0; r < 4; ++r) {
                    int row = rbase + r;
                    if (row < M) C[(size_t)row * HH + col] = acc[m][n][r] + bb;
                }
            }
        }
    } else {
        #pragma unroll
        for (int n = 0; n < 4; ++n) {
            int col = col0 + wc + n * 16 + lr;
            float gb = bias[col];
            #pragma unroll
            for (int m = 0; m < 4; ++m) {
                int rbase = row0 + wr + m * 16 + fr;
                #pragma unroll
                for (int r = 0; r < 4; ++r) {
                    int row = rbase + r;
                    if (row < M) {
                        size_t o = (size_t)row * HH + col;
                        float z = acc[m][n][r] + gb;
                        float s = 1.f / (1.f + expf(-z));
                        C[o] = s * hn[o] + (1.f - s) * fn[o] + prev[o];
                    }
                }
            }
        }
    }
}

// ---------------------------------------------------------------------------
// Row L2-normalize, emit bf16 hi/lo split
// ---------------------------------------------------------------------------
__global__ __launch_bounds__(256)
void row_norm_hl(const float* __restrict__ h, ushort* __restrict__ xh, ushort* __restrict__ xl)
{
    int n = blockIdx.x, c = threadIdx.x;
    float v = h[(size_t)n * HH + c];
    __shared__ float red[256];
    red[c] = v * v;
    __syncthreads();
    for (int s = 128; s > 0; s >>= 1) {
        if (c < s) red[c] += red[c + s];
        __syncthreads();
    }
    float norm = sqrtf(red[0]);
    float xn = v / (norm + 1e-12f);
    ushort hi = f2bf(xn);
    xh[(size_t)n * HH + c] = hi;
    xl[(size_t)n * HH + c] = f2bf(xn - bf2f(hi));
}

// ---------------------------------------------------------------------------
// top-3 helpers (exact top_k tie-breaking: value desc, index asc)
// ---------------------------------------------------------------------------
__device__ __forceinline__ bool tk_better(float va, int ia, float vb, int ib)
{
    return (va > vb) || (va == vb && ia < ib);
}

__device__ __forceinline__ void ins3(float v, int i,
                                     float& a0, int& b0, float& a1, int& b1,
                                     float& a2, int& b2)
{
    if (tk_better(v, i, a0, b0))      { a2 = a1; b2 = b1; a1 = a0; b1 = b0; a0 = v; b0 = i; }
    else if (tk_better(v, i, a1, b1)) { a2 = a1; b2 = b1; a1 = v;  b1 = i; }
    else if (tk_better(v, i, a2, b2)) { a2 = v;  b2 = i; }
}

__device__ __forceinline__ void merge3(float& v0, float& v1, float& v2,
                                       int& i0, int& i1, int& i2, int off)
{
    float w0 = __shfl_xor(v0, off), w1 = __shfl_xor(v1, off), w2 = __shfl_xor(v2, off);
    int   j0 = __shfl_xor(i0, off), j1 = __shfl_xor(i1, off), j2 = __shfl_xor(i2, off);
    float avv[3] = { v0, v1, v2 }, bvv[3] = { w0, w1, w2 };
    int   aii[3] = { i0, i1, i2 }, bii[3] = { j0, j1, j2 };
    float rv[3]; int ri[3];
    int p = 0, q = 0;
    #pragma unroll
    for (int t = 0; t < 3; ++t) {
        bool takeA = tk_better(avv[p], aii[p], bvv[q], bii[q]);
        rv[t] = takeA ? avv[p] : bvv[q];
        ri[t] = takeA ? aii[p] : bii[q];
        if (takeA) ++p; else ++q;
    }
    v0 = rv[0]; v1 = rv[1]; v2 = rv[2];
    i0 = ri[0]; i1 = ri[1]; i2 = ri[2];
}

// ---------------------------------------------------------------------------
// simtopk v3: latency-tolerant fused sim + top-3.
// Block = 64 rows of one graph (1 m-tile/wave). A fragments live in REGISTERS
// for the full K=256 (loaded once). B double-buffered in LDS in 32-k chunks
// with issue-early/write-late staging (T14): next chunk's global loads are in
// flight while MFMA consumes the current chunk. LDS rows padded to 36 ushorts
// (72B stride) -> fragment reads hit 16 distinct banks.
// XCD-swizzled grid: all 8 row-blocks of a graph share one XCD residue.
// ---------------------------------------------------------------------------
__global__ __launch_bounds__(256, 2)
void simtopk(const ushort* __restrict__ xnh, const ushort* __restrict__ xnl,
             int* __restrict__ fsrc)
{
    __shared__ ushort Bs[2][2][128][36];   // [buf][hi/lo][col][k(32)+pad4] = 36 KB
    const int bid = blockIdx.x;
    const int xcd = bid & 7;
    const int rb  = (bid >> 3) & 7;
    const int g   = (bid >> 6) * 8 + xcd;
    if (g >= GG) return;
    const int row0 = rb * 64;
    const int tid  = threadIdx.x;
    const int lane = tid & 63;
    const int w    = tid >> 6;
    const int lr   = lane & 15;
    const int hi4  = lane >> 4;
    const size_t base = (size_t)g * NPGc * HH;

    // ---- A fragments in registers: full K, wave's 16 rows ----
    int arow = row0 + w * 16 + lr; if (arow > NPGc - 1) arow = NPGc - 1;
    const ushort* aph = xnh + base + (size_t)arow * HH + hi4 * 8;
    const ushort* apl = xnl + base + (size_t)arow * HH + hi4 * 8;
    short8v ah[8], al[8];
    #pragma unroll
    for (int kc = 0; kc < 8; ++kc) {
        ah[kc] = *(const short8v*)(aph + kc * 32);
        al[kc] = *(const short8v*)(apl + kc * 32);
    }

    // staging coords: thread stages 2 consecutive 16B granules per panel
    const int scol = tid >> 1;             // 0..127
    const int sq   = (tid & 1) * 2;        // granule 0 or 2 (of 4 per 32-k chunk)

    // running top-3 per acc row r: rows row0 + w*16 + hi4*4 + r
    float tv0[4], tv1[4], tv2[4];
    int   ti0[4], ti1[4], ti2[4];
    #pragma unroll
    for (int r = 0; r < 4; ++r) {
        tv0[r] = tv1[r] = tv2[r] = -2.f;
        ti0[r] = ti1[r] = ti2[r] = 0x7fffffff;
    }

    for (int ct = 0; ct < 4; ++ct) {
        const int col0 = ct * 128;
        int gcol = col0 + scol; if (gcol > NPGc - 1) gcol = NPGc - 1;
        const ushort* sph = xnh + base + (size_t)gcol * HH + sq * 8;
        const ushort* spl = xnl + base + (size_t)gcol * HH + sq * 8;

        // prologue: stage chunk 0 into buf 0
        {
            int4 h0 = *(const int4*)(sph);
            int4 h1 = *(const int4*)(sph + 8);
            int4 l0 = *(const int4*)(spl);
            int4 l1 = *(const int4*)(spl + 8);
            *(int4*)&Bs[0][0][scol][sq * 8]     = h0;
            *(int4*)&Bs[0][0][scol][sq * 8 + 8] = h1;
            *(int4*)&Bs[0][1][scol][sq * 8]     = l0;
            *(int4*)&Bs[0][1][scol][sq * 8 + 8] = l1;
        }
        __syncthreads();

        f32x4 acc[8] = {};
        #pragma unroll
        for (int kc = 0; kc < 8; ++kc) {
            const int cur = kc & 1, nxt = cur ^ 1;
            // issue next chunk's loads FIRST (latency hides under MFMA)
            int4 h0, h1, l0, l1;
            if (kc < 7) {
                const ushort* nh = sph + (kc + 1) * 32;
                const ushort* nl = spl + (kc + 1) * 32;
                h0 = *(const int4*)(nh);
                h1 = *(const int4*)(nh + 8);
                l0 = *(const int4*)(nl);
                l1 = *(const int4*)(nl + 8);
            }
            // MFMA on current chunk
            short8v bh[8], bl[8];
            #pragma unroll
            for (int n = 0; n < 8; ++n) {
                int rr = n * 16 + lr;
                bh[n] = *(const short8v*)&Bs[cur][0][rr][hi4 * 8];
                bl[n] = *(const short8v*)&Bs[cur][1][rr][hi4 * 8];
            }
            #pragma unroll
            for (int n = 0; n < 8; ++n) {
                acc[n] = __builtin_amdgcn_mfma_f32_16x16x32_bf16(ah[kc], bh[n], acc[n], 0, 0, 0);
                acc[n] = __builtin_amdgcn_mfma_f32_16x16x32_bf16(ah[kc], bl[n], acc[n], 0, 0, 0);
                acc[n] = __builtin_amdgcn_mfma_f32_16x16x32_bf16(al[kc], bh[n], acc[n], 0, 0, 0);
            }
            // write-late: park next chunk in the other buffer
            if (kc < 7) {
                *(int4*)&Bs[nxt][0][scol][sq * 8]     = h0;
                *(int4*)&Bs[nxt][0][scol][sq * 8 + 8] = h1;
                *(int4*)&Bs[nxt][1][scol][sq * 8]     = l0;
                *(int4*)&Bs[nxt][1][scol][sq * 8 + 8] = l1;
            }
            __syncthreads();
        }

        // fold this col-tile into running top-3 (lane's col = col0 + n*16 + lr)
        #pragma unroll
        for (int n = 0; n < 8; ++n) {
            int col = col0 + n * 16 + lr;
            if (col < NPGc) {
                #pragma unroll
                for (int r = 0; r < 4; ++r)
                    ins3(acc[n][r], col, tv0[r], ti0[r], tv1[r], ti1[r], tv2[r], ti2[r]);
            }
        }
    }

    // merge across the 16 lanes sharing each row-quad (xor 1,2,4,8)
    #pragma unroll
    for (int r = 0; r < 4; ++r) {
        #pragma unroll
        for (int off = 1; off <= 8; off <<= 1)
            merge3(tv0[r], tv1[r], tv2[r], ti0[r], ti1[r], ti2[r], off);
    }

    if (lr == 0) {
        #pragma unroll
        for (int r = 0; r < 4; ++r) {
            int row = row0 + w * 16 + hi4 * 4 + r;
            if (row < NPGc) {
                int rg = g * NPGc + row;
                fsrc[rg * 3 + 0] = g * NPGc + ti0[r];
                fsrc[rg * 3 + 1] = g * NPGc + ti1[r];
                fsrc[rg * 3 + 2] = g * NPGc + ti2[r];
            }
        }
    }
}

// ---------------------------------------------------------------------------
// CSR build
// ---------------------------------------------------------------------------
__global__ void hist_kernel(const int* __restrict__ dst, int* __restrict__ cnt, int nE)
{
    int e = blockIdx.x * 256 + threadIdx.x;
    if (e < nE) atomicAdd(&cnt[dst[e]], 1);
}

__global__ void scan1_kernel(const int* __restrict__ in, int* __restrict__ out,
                             int* __restrict__ bsum, int n)
{
    __shared__ int sh[256];
    int t = threadIdx.x;
    int i = blockIdx.x * 256 + t;
    int v = (i < n) ? in[i] : 0;
    sh[t] = v;
    __syncthreads();
    for (int s = 1; s < 256; s <<= 1) {
        int tv = (t >= s) ? sh[t - s] : 0;
        __syncthreads();
        sh[t] += tv;
        __syncthreads();
    }
    if (i < n) out[i] = sh[t] - v;  // exclusive
    if (t == 255) bsum[blockIdx.x] = sh[255];
}

__global__ void scan2_kernel(int* __restrict__ bsum, int nb)
{
    __shared__ int sh[256];
    int t = threadIdx.x;
    int v = (t < nb) ? bsum[t] : 0;
    sh[t] = v;
    __syncthreads();
    for (int s = 1; s < 256; s <<= 1) {
        int tv = (t >= s) ? sh[t - s] : 0;
        __syncthreads();
        sh[t] += tv;
        __syncthreads();
    }
    if (t < nb) bsum[t] = sh[t] - v;  // exclusive block offsets
}

__global__ void scan3_kernel(int* __restrict__ out, const int* __restrict__ bsum, int n)
{
    int i = blockIdx.x * 256 + threadIdx.x;
    if (i < n) out[i] += bsum[blockIdx.x];
}

__global__ void fill_kernel(const int* __restrict__ src, const int* __restrict__ dst,
                            const int* __restrict__ row_ptr, int* __restrict__ cursor,
                            int* __restrict__ sorted_src, int nE)
{
    int e = blockIdx.x * 256 + threadIdx.x;
    if (e < nE) {
        int d = dst[e];
        int pos = row_ptr[d] + atomicAdd(&cursor[d], 1);
        sorted_src[pos] = src[e];
    }
}

__global__ void dinv_kernel(const int* __restrict__ cnt, float* __restrict__ dinv, int n)
{
    int i = blockIdx.x * 256 + threadIdx.x;
    if (i < n) dinv[i] = rsqrtf((float)cnt[i] + 1.0f);
}

// ---------------------------------------------------------------------------
// GCN gather
// ---------------------------------------------------------------------------
__global__ __launch_bounds__(256)
void gcn_gather(const float* __restrict__ m, const int* __restrict__ row_ptr,
                const int* __restrict__ cnt, const int* __restrict__ srcs,
                const float* __restrict__ dinv, const float* __restrict__ bias,
                float* __restrict__ out)
{
    int n = blockIdx.x, c = threadIdx.x;
    float dn = dinv[n];
    float acc = m[(size_t)n * HH + c] * dn;
    int s0 = row_ptr[n], e0 = s0 + cnt[n];
    for (int e = s0; e < e0; ++e) {
        int s = srcs[e];
        acc += m[(size_t)s * HH + c] * dinv[s];
    }
    out[(size_t)n * HH + c] = acc * dn + bias[c];
}

// knn-graph conv: all degrees are K+1=4 -> coef = 0.25 everywhere
__global__ __launch_bounds__(256)
void fgcn_gather(const float* __restrict__ m, const int* __restrict__ fsrc,
                 const float* __restrict__ bias, float* __restrict__ out)
{
    int n = blockIdx.x, c = threadIdx.x;
    int s0 = fsrc[n * 3], s1 = fsrc[n * 3 + 1], s2 = fsrc[n * 3 + 2];
    float acc = m[(size_t)n * HH + c] + m[(size_t)s0 * HH + c]
              + m[(size_t)s1 * HH + c] + m[(size_t)s2 * HH + c];
    out[(size_t)n * HH + c] = 0.25f * acc + bias[c];
}

// ---------------------------------------------------------------------------
// GraphNorm
// ---------------------------------------------------------------------------
__global__ __launch_bounds__(256)
void norm_stats(const float* __restrict__ x, float* __restrict__ S1, float* __restrict__ S2)
{
    int g = blockIdx.x, chunk = blockIdx.y, c = threadIdx.x;
    int r0 = chunk * 63, r1 = min(r0 + 63, NPGc);
    float s1 = 0.f, s2 = 0.f;
    for (int r = r0; r < r1; ++r) {
        float v = x[((size_t)(g * NPGc + r)) * HH + c];
        s1 += v; s2 += v * v;
    }
    atomicAdd(&S1[g * HH + c], s1);
    atomicAdd(&S2[g * HH + c], s2);
}

__global__ __launch_bounds__(256)
void norm_apply(float* __restrict__ x, const float* __restrict__ S1, const float* __restrict__ S2,
                const float* __restrict__ w, const float* __restrict__ b,
                const float* __restrict__ ms)
{
    int n = blockIdx.x, c = threadIdx.x;
    int g = n / NPGc;
    size_t o = (size_t)n * HH + c;
    float v = x[o];
    float mean = S1[g * HH + c] / (float)NPGc;
    float mm = mean * ms[c];
    float var = S2[g * HH + c] / (float)NPGc - 2.f * mm * mean + mm * mm;
    float outv = w[c] * (v - mm) * rsqrtf(var + 1e-5f) + b[c];
    x[o] = outv > 0.f ? outv : 0.01f * outv;
}

// ---------------------------------------------------------------------------
// Pool: gf[g] = (sum X0 + 2*sum X1) / 500   (all_x[-1]==all_x[1] quirk)
// ---------------------------------------------------------------------------
__global__ __launch_bounds__(256)
void pool_kernel(const float* __restrict__ X0, const float* __restrict__ X1,
                 float* __restrict__ out)
{
    int g = blockIdx.x, c = threadIdx.x;
    float s0 = 0.f, s1 = 0.f;
    for (int r = 0; r < NPGc; ++r) {
        size_t o = ((size_t)(g * NPGc + r)) * HH + c;
        s0 += X0[o];
        s1 += X1[o];
    }
    out[g * HH + c] = (s0 + 2.f * s1) / (float)NPGc;
}

__global__ void sentinel_kernel(float* out, int n)
{
    int i = blockIdx.x * 256 + threadIdx.x;
    if (i < n) out[i] = 12345.0f;
}

// ---------------------------------------------------------------------------
extern "C" void kernel_launch(void* const* d_in, const int* in_sizes, int n_in,
                              void* d_out, int out_size, void* d_ws, size_t ws_size,
                              hipStream_t stream)
{
    const float* x       = (const float*)d_in[0];
    const int* edge_idx  = (const int*)d_in[1];
    const float* emb_W   = (const float*)d_in[3];
    const float* emb_b   = (const float*)d_in[4];
    const float* conv_W  = (const float*)d_in[5];
    const float* conv_b  = (const float*)d_in[6];
    const float* fconv_W = (const float*)d_in[7];
    const float* fconv_b = (const float*)d_in[8];
    const float* norm_w  = (const float*)d_in[9];
    const float* norm_b  = (const float*)d_in[10];
    const float* norm_ms = (const float*)d_in[11];
    const float* fnorm_w = (const float*)d_in[12];
    const float* fnorm_b = (const float*)d_in[13];
    const float* fnorm_ms= (const float*)d_in[14];
    const float* gate_W  = (const float*)d_in[15];
    const float* gate_b  = (const float*)d_in[16];

    const int E = in_sizes[1] / 2;
    const int* esrc = edge_idx;
    const int* edst = edge_idx + E;

    const size_t NHf = (size_t)NN * HH;           // 12.8M elements
    char* p = (char*)d_ws;
    auto alloc = [&](size_t bytes) { char* r = p; p += (bytes + 255) & ~(size_t)255; return r; };
    float* B0 = (float*)alloc(NHf * 4);
    float* B1 = (float*)alloc(NHf * 4);
    float* B2 = (float*)alloc(NHf * 4);
    float* B3 = (float*)alloc(NHf * 4);
    ushort* xnh = (ushort*)B2;          // 25.6MB overlay, dead once layers start
    ushort* xnl = xnh + NHf;            // 25.6MB (rest of B2)
    int* sorted_src = (int*)alloc((size_t)E * 4);
    int* row_ptr    = (int*)alloc((size_t)NN * 4);
    int* deg_cnt    = (int*)alloc((size_t)NN * 4);
    int* cursor     = (int*)alloc((size_t)NN * 4);
    float* dinv     = (float*)alloc((size_t)NN * 4);
    int* fsrc       = (int*)alloc((size_t)NN * 3 * 4);
    float* S1       = (float*)alloc((size_t)GG * HH * 4);
    float* S2       = (float*)alloc((size_t)GG * HH * 4);
    int* bsum       = (int*)alloc(1024);
    ushort* wts     = (ushort*)alloc((size_t)425984 * 2);  // all W^T bf16
    size_t needed = (size_t)(p - (char*)d_ws);
    if (ws_size < needed) {
        sentinel_kernel<<<(out_size + 255) / 256, 256, 0, stream>>>((float*)d_out, out_size);
        return;
    }
    ushort* embWt   = wts;                    // [256][128]
    ushort* convWt0 = wts + 32768;            // [256][256]
    ushort* convWt1 = wts + 32768 + 65536;
    ushort* fconvWt0 = wts + 163840;
    ushort* fconvWt1 = wts + 163840 + 65536;
    ushort* gateWt  = wts + 294912;           // [256][512]

    const int nScanB = (NN + 255) / 256;  // 196

    hipMemsetAsync(deg_cnt, 0, (size_t)NN * 4, stream);
    hipMemsetAsync(cursor, 0, (size_t)NN * 4, stream);

    // 0. weight transpose+cvt
    wcvt<<<(32768 + 255) / 256, 256, 0, stream>>>(emb_W, embWt, IND, HH);
    wcvt<<<(65536 + 255) / 256, 256, 0, stream>>>(conv_W, convWt0, HH, HH);
    wcvt<<<(65536 + 255) / 256, 256, 0, stream>>>(conv_W + 65536, convWt1, HH, HH);
    wcvt<<<(65536 + 255) / 256, 256, 0, stream>>>(fconv_W, fconvWt0, HH, HH);
    wcvt<<<(65536 + 255) / 256, 256, 0, stream>>>(fconv_W + 65536, fconvWt1, HH, HH);
    wcvt<<<(131072 + 255) / 256, 256, 0, stream>>>(gate_W, gateWt, 2 * HH, HH);

    // 1. embedding: h0 = x @ emb_W + emb_b -> B0
    dim3 ggrid((NN + 127) / 128, 2);
    gemm_mfma<<<ggrid, 256, 0, stream>>>(x, nullptr, embWt, emb_b, B0, NN, IND, IND, 0,
                                         nullptr, nullptr, nullptr);

    // 2. CSR of edge_index by dst
    hist_kernel<<<(E + 255) / 256, 256, 0, stream>>>(edst, deg_cnt, E);
    scan1_kernel<<<nScanB, 256, 0, stream>>>(deg_cnt, row_ptr, bsum, NN);
    scan2_kernel<<<1, 256, 0, stream>>>(bsum, nScanB);
    scan3_kernel<<<nScanB, 256, 0, stream>>>(row_ptr, bsum, NN);
    fill_kernel<<<(E + 255) / 256, 256, 0, stream>>>(esrc, edst, row_ptr, cursor, sorted_src, E);
    dinv_kernel<<<(NN + 255) / 256, 256, 0, stream>>>(deg_cnt, dinv, NN);

    // 3. knn graph from h0 (hi/lo split, reg-A + dbuf-B fused sim+topk)
    row_norm_hl<<<NN, 256, 0, stream>>>(B0, xnh, xnl);
    simtopk<<<832, 256, 0, stream>>>(xnh, xnl, fsrc);   // 13 clusters x 64 (XCD-swizzled)

    // 4. layers
    float* h  = B0;
    float* mb = B1;
    dim3 ngrid(GG, 8);
    for (int i = 0; i < 2; ++i) {
        const ushort* Wc = (i == 0) ? convWt0 : convWt1;
        const ushort* Wf = (i == 0) ? fconvWt0 : fconvWt1;
        const float* bc  = conv_b  + (size_t)i * HH;
        const float* bf  = fconv_b + (size_t)i * HH;
        // h-road conv
        gemm_mfma<<<ggrid, 256, 0, stream>>>(h, nullptr, Wc, nullptr, mb, NN, HH, HH, 0,
                                             nullptr, nullptr, nullptr);
        gcn_gather<<<NN, 256, 0, stream>>>(mb, row_ptr, deg_cnt, sorted_src, dinv, bc, B2);
        hipMemsetAsync(S1, 0, (size_t)2 * GG * HH * 4, stream);
        norm_stats<<<ngrid, 256, 0, stream>>>(B2, S1, S2);
        norm_apply<<<NN, 256, 0, stream>>>(B2, S1, S2, norm_w + i * HH, norm_b + i * HH,
                                           norm_ms + i * HH);
        // f-road conv (knn graph)
        gemm_mfma<<<ggrid, 256, 0, stream>>>(B2, nullptr, Wf, nullptr, mb, NN, HH, HH, 0,
                                             nullptr, nullptr, nullptr);
        fgcn_gather<<<NN, 256, 0, stream>>>(mb, fsrc, bf, B3);
        hipMemsetAsync(S1, 0, (size_t)2 * GG * HH * 4, stream);
        norm_stats<<<ngrid, 256, 0, stream>>>(B3, S1, S2);
        norm_apply<<<NN, 256, 0, stream>>>(B3, S1, S2, fnorm_w + i * HH, fnorm_b + i * HH,
                                           fnorm_ms + i * HH);
        // gate + combine
        gemm_mfma<<<ggrid, 256, 0, stream>>>(B2, B3, gateWt, gate_b, mb, NN, 2 * HH, HH, 1,
                                             B2, B3, h);
        float* t = h; h = mb; mb = t;
    }
    // h = all_x[1], mb = all_x[0]
    pool_kernel<<<GG, 256, 0, stream>>>(mb, h, (float*)d_out);
}

// Round 8
// 1296.226 us; speedup vs baseline: 1.2873x; 1.0579x over previous
//
#include <hip/hip_runtime.h>
#include <math.h>

#define NN 50000      // nodes
#define GG 100        // graphs
#define NPGc 500      // nodes per graph
#define HH 256        // hidden
#define IND 128       // input dim

typedef __attribute__((ext_vector_type(8))) short short8v;  // 8 bf16
typedef __attribute__((ext_vector_type(4))) float f32x4;

__device__ __forceinline__ ushort f2bf(float f) {
    union { float f; unsigned u; } v; v.f = f;
    unsigned r = (v.u + 0x7fffu + ((v.u >> 16) & 1u)) >> 16;  // RNE
    return (ushort)r;
}
__device__ __forceinline__ float bf2f(ushort h) {
    union { unsigned u; float f; } v; v.u = ((unsigned)h) << 16;
    return v.f;
}

// LDS ushort-index swizzle: XOR 16B-granule bits with row&7 (T2, bank-conflict fix)
__device__ __forceinline__ int swz(int row, int kidx) { return kidx ^ ((row & 7) << 3); }

// ---------------------------------------------------------------------------
// Weight transpose+convert: src [K][N] f32 -> dst [N][K] bf16
// ---------------------------------------------------------------------------
__global__ void wcvt(const float* __restrict__ src, ushort* __restrict__ dst, int K, int N)
{
    int i = blockIdx.x * 256 + threadIdx.x;
    if (i < K * N) {
        int n = i / K, k = i % K;
        dst[i] = f2bf(src[(size_t)k * N + n]);
    }
}

// ---------------------------------------------------------------------------
// bf16 MFMA GEMM: C[M x 256] = A[M x K](f32, cvt on stage) @ Wt[N=256][K](bf16)
// tile 128x128, BK=64, 4 waves each 64x64. LDS XOR-swizzled.
// mode 0: C=f32 acc(+bias). mode 1: gate epilogue. mode 2: Cbf=bf16 acc(+bias).
// ---------------------------------------------------------------------------
__global__ __launch_bounds__(256)
void gemm_mfma(const float* __restrict__ A, const float* __restrict__ A2,
               const ushort* __restrict__ Wt, const float* __restrict__ bias,
               float* __restrict__ C, ushort* __restrict__ Cbf,
               int M, int K, int lda, int mode,
               const float* __restrict__ hn, const float* __restrict__ fn,
               const float* __restrict__ prev)
{
    __shared__ ushort As[128][64];
    __shared__ ushort Bs[128][64];
    const int tid = threadIdx.x;
    const int lane = tid & 63;
    const int w = tid >> 6;
    const int wr = (w >> 1) * 64, wc = (w & 1) * 64;
    const int row0 = blockIdx.x * 128, col0 = blockIdx.y * 128;
    const int lr = lane & 15, lk = (lane >> 4) * 8;
    f32x4 acc[4][4] = {};

    for (int k0 = 0; k0 < K; k0 += 64) {
        __syncthreads();
        #pragma unroll
        for (int it = 0; it < 4; ++it) {           // stage A: 128x64, f32->bf16
            int c = it * 256 + tid;
            int row = c >> 3, col = (c & 7) * 8;
            int gr = row0 + row; if (gr > M - 1) gr = M - 1;
            const float* Ap = A; int kk = k0 + col;
            if (A2 != nullptr && kk >= 256) { Ap = A2; kk -= 256; }
            const float* s = &Ap[(size_t)gr * lda + kk];
            float4 v0 = *(const float4*)s;
            float4 v1 = *(const float4*)(s + 4);
            union { ushort u[8]; int4 q; } pk;
            pk.u[0] = f2bf(v0.x); pk.u[1] = f2bf(v0.y); pk.u[2] = f2bf(v0.z); pk.u[3] = f2bf(v0.w);
            pk.u[4] = f2bf(v1.x); pk.u[5] = f2bf(v1.y); pk.u[6] = f2bf(v1.z); pk.u[7] = f2bf(v1.w);
            *(int4*)&As[row][swz(row, col)] = pk.q;
        }
        #pragma unroll
        for (int it = 0; it < 4; ++it) {           // stage B: Wt rows col0..+127
            int c = it * 256 + tid;
            int n = c >> 3, k = (c & 7) * 8;
            *(int4*)&Bs[n][swz(n, k)] = *(const int4*)&Wt[(size_t)(col0 + n) * K + k0 + k];
        }
        __syncthreads();
        #pragma unroll
        for (int ks = 0; ks < 2; ++ks) {
            short8v av[4], bv[4];
            #pragma unroll
            for (int m = 0; m < 4; ++m) {
                int rr = wr + m * 16 + lr;
                av[m] = *(const short8v*)&As[rr][swz(rr, ks * 32 + lk)];
            }
            #pragma unroll
            for (int n = 0; n < 4; ++n) {
                int rr = wc + n * 16 + lr;
                bv[n] = *(const short8v*)&Bs[rr][swz(rr, ks * 32 + lk)];
            }
            #pragma unroll
            for (int m = 0; m < 4; ++m)
                #pragma unroll
                for (int n = 0; n < 4; ++n)
                    acc[m][n] = __builtin_amdgcn_mfma_f32_16x16x32_bf16(av[m], bv[n], acc[m][n], 0, 0, 0);
        }
    }
    const int fr = (lane >> 4) * 4;
    if (mode == 0) {
        #pragma unroll
        for (int n = 0; n < 4; ++n) {
            int col = col0 + wc + n * 16 + lr;
            float bb = bias ? bias[col] : 0.f;
            #pragma unroll
            for (int m = 0; m < 4; ++m) {
                int rbase = row0 + wr + m * 16 + fr;
                #pragma unroll
                for (int r = 0; r < 4; ++r) {
                    int row = rbase + r;
                    if (row < M) C[(size_t)row * HH + col] = acc[m][n][r] + bb;
                }
            }
        }
    } else if (mode == 2) {
        #pragma unroll
        for (int n = 0; n < 4; ++n) {
            int col = col0 + wc + n * 16 + lr;
            float bb = bias ? bias[col] : 0.f;
            #pragma unroll
            for (int m = 0; m < 4; ++m) {
                int rbase = row0 + wr + m * 16 + fr;
                #pragma unroll
                for (int r = 0; r < 4; ++r) {
                    int row = rbase + r;
                    if (row < M) Cbf[(size_t)row * HH + col] = f2bf(acc[m][n][r] + bb);
                }
            }
        }
    } else {
        #pragma unroll
        for (int n = 0; n < 4; ++n) {
            int col = col0 + wc + n * 16 + lr;
            float gb = bias[col];
            #pragma unroll
            for (int m = 0; m < 4; ++m) {
                int rbase = row0 + wr + m * 16 + fr;
                #pragma unroll
                for (int r = 0; r < 4; ++r) {
                    int row = rbase + r;
                    if (row < M) {
                        size_t o = (size_t)row * HH + col;
                        float z = acc[m][n][r] + gb;
                        float s = 1.f / (1.f + expf(-z));
                        C[o] = s * hn[o] + (1.f - s) * fn[o] + prev[o];
                    }
                }
            }
        }
    }
}

// ---------------------------------------------------------------------------
// Row L2-normalize, emit bf16 hi/lo split
// ---------------------------------------------------------------------------
__global__ __launch_bounds__(256)
void row_norm_hl(const float* __restrict__ h, ushort* __restrict__ xh, ushort* __restrict__ xl)
{
    int n = blockIdx.x, c = threadIdx.x;
    float v = h[(size_t)n * HH + c];
    __shared__ float red[256];
    red[c] = v * v;
    __syncthreads();
    for (int s = 128; s > 0; s >>= 1) {
        if (c < s) red[c] += red[c + s];
        __syncthreads();
    }
    float norm = sqrtf(red[0]);
    float xn = v / (norm + 1e-12f);
    ushort hi = f2bf(xn);
    xh[(size_t)n * HH + c] = hi;
    xl[(size_t)n * HH + c] = f2bf(xn - bf2f(hi));
}

// ---------------------------------------------------------------------------
// top-3 helpers (exact top_k tie-breaking: value desc, index asc)
// ---------------------------------------------------------------------------
__device__ __forceinline__ bool tk_better(float va, int ia, float vb, int ib)
{
    return (va > vb) || (va == vb && ia < ib);
}

__device__ __forceinline__ void ins3(float v, int i,
                                     float& a0, int& b0, float& a1, int& b1,
                                     float& a2, int& b2)
{
    if (tk_better(v, i, a0, b0))      { a2 = a1; b2 = b1; a1 = a0; b1 = b0; a0 = v; b0 = i; }
    else if (tk_better(v, i, a1, b1)) { a2 = a1; b2 = b1; a1 = v;  b1 = i; }
    else if (tk_better(v, i, a2, b2)) { a2 = v;  b2 = i; }
}

__device__ __forceinline__ void merge3(float& v0, float& v1, float& v2,
                                       int& i0, int& i1, int& i2, int off)
{
    float w0 = __shfl_xor(v0, off), w1 = __shfl_xor(v1, off), w2 = __shfl_xor(v2, off);
    int   j0 = __shfl_xor(i0, off), j1 = __shfl_xor(i1, off), j2 = __shfl_xor(i2, off);
    float avv[3] = { v0, v1, v2 }, bvv[3] = { w0, w1, w2 };
    int   aii[3] = { i0, i1, i2 }, bii[3] = { j0, j1, j2 };
    float rv[3]; int ri[3];
    int p = 0, q = 0;
    #pragma unroll
    for (int t = 0; t < 3; ++t) {
        bool takeA = tk_better(avv[p], aii[p], bvv[q], bii[q]);
        rv[t] = takeA ? avv[p] : bvv[q];
        ri[t] = takeA ? aii[p] : bii[q];
        if (takeA) ++p; else ++q;
    }
    v0 = rv[0]; v1 = rv[1]; v2 = rv[2];
    i0 = ri[0]; i1 = ri[1]; i2 = ri[2];
}

// ---------------------------------------------------------------------------
// simtopk: reg-A + dbuf-B fused sim + top-3 (as round 7) but with
// __launch_bounds__(256,1): 256-VGPR budget so A-fragments/acc/top-3 state
// fit in registers (spill-elimination theory; round 7 allocated only 108
// VGPRs for ~200 live values -> scratch round-trips dominated).
// ---------------------------------------------------------------------------
__global__ __launch_bounds__(256, 1)
void simtopk(const ushort* __restrict__ xnh, const ushort* __restrict__ xnl,
             int* __restrict__ fsrc)
{
    __shared__ ushort Bs[2][2][128][36];   // [buf][hi/lo][col][k(32)+pad4] = 36 KB
    const int bid = blockIdx.x;
    const int xcd = bid & 7;
    const int rb  = (bid >> 3) & 7;
    const int g   = (bid >> 6) * 8 + xcd;
    if (g >= GG) return;
    const int row0 = rb * 64;
    const int tid  = threadIdx.x;
    const int lane = tid & 63;
    const int w    = tid >> 6;
    const int lr   = lane & 15;
    const int hi4  = lane >> 4;
    const size_t base = (size_t)g * NPGc * HH;

    // ---- A fragments in registers: full K, wave's 16 rows ----
    int arow = row0 + w * 16 + lr; if (arow > NPGc - 1) arow = NPGc - 1;
    const ushort* aph = xnh + base + (size_t)arow * HH + hi4 * 8;
    const ushort* apl = xnl + base + (size_t)arow * HH + hi4 * 8;
    short8v ah[8], al[8];
    #pragma unroll
    for (int kc = 0; kc < 8; ++kc) {
        ah[kc] = *(const short8v*)(aph + kc * 32);
        al[kc] = *(const short8v*)(apl + kc * 32);
    }

    // staging coords: thread stages 2 consecutive 16B granules per panel
    const int scol = tid >> 1;             // 0..127
    const int sq   = (tid & 1) * 2;        // granule 0 or 2 (of 4 per 32-k chunk)

    // running top-3 per acc row r: rows row0 + w*16 + hi4*4 + r
    float tv0[4], tv1[4], tv2[4];
    int   ti0[4], ti1[4], ti2[4];
    #pragma unroll
    for (int r = 0; r < 4; ++r) {
        tv0[r] = tv1[r] = tv2[r] = -2.f;
        ti0[r] = ti1[r] = ti2[r] = 0x7fffffff;
    }

    for (int ct = 0; ct < 4; ++ct) {
        const int col0 = ct * 128;
        int gcol = col0 + scol; if (gcol > NPGc - 1) gcol = NPGc - 1;
        const ushort* sph = xnh + base + (size_t)gcol * HH + sq * 8;
        const ushort* spl = xnl + base + (size_t)gcol * HH + sq * 8;

        // prologue: stage chunk 0 into buf 0
        {
            int4 h0 = *(const int4*)(sph);
            int4 h1 = *(const int4*)(sph + 8);
            int4 l0 = *(const int4*)(spl);
            int4 l1 = *(const int4*)(spl + 8);
            *(int4*)&Bs[0][0][scol][sq * 8]     = h0;
            *(int4*)&Bs[0][0][scol][sq * 8 + 8] = h1;
            *(int4*)&Bs[0][1][scol][sq * 8]     = l0;
            *(int4*)&Bs[0][1][scol][sq * 8 + 8] = l1;
        }
        __syncthreads();

        f32x4 acc[8] = {};
        #pragma unroll
        for (int kc = 0; kc < 8; ++kc) {
            const int cur = kc & 1, nxt = cur ^ 1;
            // issue next chunk's loads FIRST (latency hides under MFMA)
            int4 h0, h1, l0, l1;
            if (kc < 7) {
                const ushort* nh = sph + (kc + 1) * 32;
                const ushort* nl = spl + (kc + 1) * 32;
                h0 = *(const int4*)(nh);
                h1 = *(const int4*)(nh + 8);
                l0 = *(const int4*)(nl);
                l1 = *(const int4*)(nl + 8);
            }
            // MFMA on current chunk
            short8v bh[8], bl[8];
            #pragma unroll
            for (int n = 0; n < 8; ++n) {
                int rr = n * 16 + lr;
                bh[n] = *(const short8v*)&Bs[cur][0][rr][hi4 * 8];
                bl[n] = *(const short8v*)&Bs[cur][1][rr][hi4 * 8];
            }
            #pragma unroll
            for (int n = 0; n < 8; ++n) {
                acc[n] = __builtin_amdgcn_mfma_f32_16x16x32_bf16(ah[kc], bh[n], acc[n], 0, 0, 0);
                acc[n] = __builtin_amdgcn_mfma_f32_16x16x32_bf16(ah[kc], bl[n], acc[n], 0, 0, 0);
                acc[n] = __builtin_amdgcn_mfma_f32_16x16x32_bf16(al[kc], bh[n], acc[n], 0, 0, 0);
            }
            // write-late: park next chunk in the other buffer
            if (kc < 7) {
                *(int4*)&Bs[nxt][0][scol][sq * 8]     = h0;
                *(int4*)&Bs[nxt][0][scol][sq * 8 + 8] = h1;
                *(int4*)&Bs[nxt][1][scol][sq * 8]     = l0;
                *(int4*)&Bs[nxt][1][scol][sq * 8 + 8] = l1;
            }
            __syncthreads();
        }

        // fold this col-tile into running top-3 (lane's col = col0 + n*16 + lr)
        #pragma unroll
        for (int n = 0; n < 8; ++n) {
            int col = col0 + n * 16 + lr;
            if (col < NPGc) {
                #pragma unroll
                for (int r = 0; r < 4; ++r)
                    ins3(acc[n][r], col, tv0[r], ti0[r], tv1[r], ti1[r], tv2[r], ti2[r]);
            }
        }
    }

    // merge across the 16 lanes sharing each row-quad (xor 1,2,4,8)
    #pragma unroll
    for (int r = 0; r < 4; ++r) {
        #pragma unroll
        for (int off = 1; off <= 8; off <<= 1)
            merge3(tv0[r], tv1[r], tv2[r], ti0[r], ti1[r], ti2[r], off);
    }

    if (lr == 0) {
        #pragma unroll
        for (int r = 0; r < 4; ++r) {
            int row = row0 + w * 16 + hi4 * 4 + r;
            if (row < NPGc) {
                int rg = g * NPGc + row;
                fsrc[rg * 3 + 0] = g * NPGc + ti0[r];
                fsrc[rg * 3 + 1] = g * NPGc + ti1[r];
                fsrc[rg * 3 + 2] = g * NPGc + ti2[r];
            }
        }
    }
}

// ---------------------------------------------------------------------------
// CSR build
// ---------------------------------------------------------------------------
__global__ void hist_kernel(const int* __restrict__ dst, int* __restrict__ cnt, int nE)
{
    int e = blockIdx.x * 256 + threadIdx.x;
    if (e < nE) atomicAdd(&cnt[dst[e]], 1);
}

__global__ void scan1_kernel(const int* __restrict__ in, int* __restrict__ out,
                             int* __restrict__ bsum, int n)
{
    __shared__ int sh[256];
    int t = threadIdx.x;
    int i = blockIdx.x * 256 + t;
    int v = (i < n) ? in[i] : 0;
    sh[t] = v;
    __syncthreads();
    for (int s = 1; s < 256; s <<= 1) {
        int tv = (t >= s) ? sh[t - s] : 0;
        __syncthreads();
        sh[t] += tv;
        __syncthreads();
    }
    if (i < n) out[i] = sh[t] - v;  // exclusive
    if (t == 255) bsum[blockIdx.x] = sh[255];
}

__global__ void scan2_kernel(int* __restrict__ bsum, int nb)
{
    __shared__ int sh[256];
    int t = threadIdx.x;
    int v = (t < nb) ? bsum[t] : 0;
    sh[t] = v;
    __syncthreads();
    for (int s = 1; s < 256; s <<= 1) {
        int tv = (t >= s) ? sh[t - s] : 0;
        __syncthreads();
        sh[t] += tv;
        __syncthreads();
    }
    if (t < nb) bsum[t] = sh[t] - v;  // exclusive block offsets
}

__global__ void scan3_kernel(int* __restrict__ out, const int* __restrict__ bsum, int n)
{
    int i = blockIdx.x * 256 + threadIdx.x;
    if (i < n) out[i] += bsum[blockIdx.x];
}

__global__ void fill_kernel(const int* __restrict__ src, const int* __restrict__ dst,
                            const int* __restrict__ row_ptr, int* __restrict__ cursor,
                            int* __restrict__ sorted_src, int nE)
{
    int e = blockIdx.x * 256 + threadIdx.x;
    if (e < nE) {
        int d = dst[e];
        int pos = row_ptr[d] + atomicAdd(&cursor[d], 1);
        sorted_src[pos] = src[e];
    }
}

__global__ void dinv_kernel(const int* __restrict__ cnt, float* __restrict__ dinv, int n)
{
    int i = blockIdx.x * 256 + threadIdx.x;
    if (i < n) dinv[i] = rsqrtf((float)cnt[i] + 1.0f);
}

// ---------------------------------------------------------------------------
// GCN gather (bf16 messages, XCD-bijective swizzle: graph g -> XCD g%8)
// grid = 8 * 13 * 500 = 52000, blocks with g >= 100 exit.
// ---------------------------------------------------------------------------
__global__ __launch_bounds__(256)
void gcn_gather(const ushort* __restrict__ m, const int* __restrict__ row_ptr,
                const int* __restrict__ cnt, const int* __restrict__ srcs,
                const float* __restrict__ dinv, const float* __restrict__ bias,
                float* __restrict__ out)
{
    int bid = blockIdx.x;
    int xcd = bid & 7, idx = bid >> 3;
    int g = xcd + 8 * (idx / NPGc);
    if (g >= GG) return;
    int n = g * NPGc + (idx % NPGc);
    int c = threadIdx.x;
    float dn = dinv[n];
    float acc = bf2f(m[(size_t)n * HH + c]) * dn;
    int s0 = row_ptr[n], e0 = s0 + cnt[n];
    for (int e = s0; e < e0; ++e) {
        int s = srcs[e];
        acc += bf2f(m[(size_t)s * HH + c]) * dinv[s];
    }
    out[(size_t)n * HH + c] = acc * dn + bias[c];
}

// knn-graph conv: all degrees are K+1=4 -> coef = 0.25 everywhere
__global__ __launch_bounds__(256)
void fgcn_gather(const ushort* __restrict__ m, const int* __restrict__ fsrc,
                 const float* __restrict__ bias, float* __restrict__ out)
{
    int bid = blockIdx.x;
    int xcd = bid & 7, idx = bid >> 3;
    int g = xcd + 8 * (idx / NPGc);
    if (g >= GG) return;
    int n = g * NPGc + (idx % NPGc);
    int c = threadIdx.x;
    int s0 = fsrc[n * 3], s1 = fsrc[n * 3 + 1], s2 = fsrc[n * 3 + 2];
    float acc = bf2f(m[(size_t)n * HH + c]) + bf2f(m[(size_t)s0 * HH + c])
              + bf2f(m[(size_t)s1 * HH + c]) + bf2f(m[(size_t)s2 * HH + c]);
    out[(size_t)n * HH + c] = 0.25f * acc + bias[c];
}

// ---------------------------------------------------------------------------
// GraphNorm
// ---------------------------------------------------------------------------
__global__ __launch_bounds__(256)
void norm_stats(const float* __restrict__ x, float* __restrict__ S1, float* __restrict__ S2)
{
    int g = blockIdx.x, chunk = blockIdx.y, c = threadIdx.x;
    int r0 = chunk * 63, r1 = min(r0 + 63, NPGc);
    float s1 = 0.f, s2 = 0.f;
    for (int r = r0; r < r1; ++r) {
        float v = x[((size_t)(g * NPGc + r)) * HH + c];
        s1 += v; s2 += v * v;
    }
    atomicAdd(&S1[g * HH + c], s1);
    atomicAdd(&S2[g * HH + c], s2);
}

__global__ __launch_bounds__(256)
void norm_apply(float* __restrict__ x, const float* __restrict__ S1, const float* __restrict__ S2,
                const float* __restrict__ w, const float* __restrict__ b,
                const float* __restrict__ ms)
{
    int n = blockIdx.x, c = threadIdx.x;
    int g = n / NPGc;
    size_t o = (size_t)n * HH + c;
    float v = x[o];
    float mean = S1[g * HH + c] / (float)NPGc;
    float mm = mean * ms[c];
    float var = S2[g * HH + c] / (float)NPGc - 2.f * mm * mean + mm * mm;
    float outv = w[c] * (v - mm) * rsqrtf(var + 1e-5f) + b[c];
    x[o] = outv > 0.f ? outv : 0.01f * outv;
}

// ---------------------------------------------------------------------------
// Pool: gf[g] = (sum X0 + 2*sum X1) / 500   (all_x[-1]==all_x[1] quirk)
// ---------------------------------------------------------------------------
__global__ __launch_bounds__(256)
void pool_kernel(const float* __restrict__ X0, const float* __restrict__ X1,
                 float* __restrict__ out)
{
    int g = blockIdx.x, c = threadIdx.x;
    float s0 = 0.f, s1 = 0.f;
    for (int r = 0; r < NPGc; ++r) {
        size_t o = ((size_t)(g * NPGc + r)) * HH + c;
        s0 += X0[o];
        s1 += X1[o];
    }
    out[g * HH + c] = (s0 + 2.f * s1) / (float)NPGc;
}

__global__ void sentinel_kernel(float* out, int n)
{
    int i = blockIdx.x * 256 + threadIdx.x;
    if (i < n) out[i] = 12345.0f;
}

// ---------------------------------------------------------------------------
extern "C" void kernel_launch(void* const* d_in, const int* in_sizes, int n_in,
                              void* d_out, int out_size, void* d_ws, size_t ws_size,
                              hipStream_t stream)
{
    const float* x       = (const float*)d_in[0];
    const int* edge_idx  = (const int*)d_in[1];
    const float* emb_W   = (const float*)d_in[3];
    const float* emb_b   = (const float*)d_in[4];
    const float* conv_W  = (const float*)d_in[5];
    const float* conv_b  = (const float*)d_in[6];
    const float* fconv_W = (const float*)d_in[7];
    const float* fconv_b = (const float*)d_in[8];
    const float* norm_w  = (const float*)d_in[9];
    const float* norm_b  = (const float*)d_in[10];
    const float* norm_ms = (const float*)d_in[11];
    const float* fnorm_w = (const float*)d_in[12];
    const float* fnorm_b = (const float*)d_in[13];
    const float* fnorm_ms= (const float*)d_in[14];
    const float* gate_W  = (const float*)d_in[15];
    const float* gate_b  = (const float*)d_in[16];

    const int E = in_sizes[1] / 2;
    const int* esrc = edge_idx;
    const int* edst = edge_idx + E;

    const size_t NHf = (size_t)NN * HH;           // 12.8M elements
    char* p = (char*)d_ws;
    auto alloc = [&](size_t bytes) { char* r = p; p += (bytes + 255) & ~(size_t)255; return r; };
    float* B0 = (float*)alloc(NHf * 4);
    float* B1 = (float*)alloc(NHf * 4);
    float* B2 = (float*)alloc(NHf * 4);
    float* B3 = (float*)alloc(NHf * 4);
    ushort* xnh = (ushort*)B2;          // 25.6MB overlay, dead once layers start
    ushort* xnl = xnh + NHf;            // 25.6MB (rest of B2)
    ushort* msgbf = (ushort*)alloc(NHf * 2);  // bf16 message buffer
    int* sorted_src = (int*)alloc((size_t)E * 4);
    int* row_ptr    = (int*)alloc((size_t)NN * 4);
    int* deg_cnt    = (int*)alloc((size_t)NN * 4);
    int* cursor     = (int*)alloc((size_t)NN * 4);
    float* dinv     = (float*)alloc((size_t)NN * 4);
    int* fsrc       = (int*)alloc((size_t)NN * 3 * 4);
    float* S1       = (float*)alloc((size_t)GG * HH * 4);
    float* S2       = (float*)alloc((size_t)GG * HH * 4);
    int* bsum       = (int*)alloc(1024);
    ushort* wts     = (ushort*)alloc((size_t)425984 * 2);  // all W^T bf16
    size_t needed = (size_t)(p - (char*)d_ws);
    if (ws_size < needed) {
        sentinel_kernel<<<(out_size + 255) / 256, 256, 0, stream>>>((float*)d_out, out_size);
        return;
    }
    ushort* embWt   = wts;                    // [256][128]
    ushort* convWt0 = wts + 32768;            // [256][256]
    ushort* convWt1 = wts + 32768 + 65536;
    ushort* fconvWt0 = wts + 163840;
    ushort* fconvWt1 = wts + 163840 + 65536;
    ushort* gateWt  = wts + 294912;           // [256][512]

    const int nScanB = (NN + 255) / 256;  // 196
    const int gatherGrid = 8 * 13 * NPGc; // 52000 (XCD-bijective, skip g>=100)

    hipMemsetAsync(deg_cnt, 0, (size_t)NN * 4, stream);
    hipMemsetAsync(cursor, 0, (size_t)NN * 4, stream);

    // 0. weight transpose+cvt
    wcvt<<<(32768 + 255) / 256, 256, 0, stream>>>(emb_W, embWt, IND, HH);
    wcvt<<<(65536 + 255) / 256, 256, 0, stream>>>(conv_W, convWt0, HH, HH);
    wcvt<<<(65536 + 255) / 256, 256, 0, stream>>>(conv_W + 65536, convWt1, HH, HH);
    wcvt<<<(65536 + 255) / 256, 256, 0, stream>>>(fconv_W, fconvWt0, HH, HH);
    wcvt<<<(65536 + 255) / 256, 256, 0, stream>>>(fconv_W + 65536, fconvWt1, HH, HH);
    wcvt<<<(131072 + 255) / 256, 256, 0, stream>>>(gate_W, gateWt, 2 * HH, HH);

    // 1. embedding: h0 = x @ emb_W + emb_b -> B0
    dim3 ggrid((NN + 127) / 128, 2);
    gemm_mfma<<<ggrid, 256, 0, stream>>>(x, nullptr, embWt, emb_b, B0, nullptr,
                                         NN, IND, IND, 0, nullptr, nullptr, nullptr);

    // 2. CSR of edge_index by dst
    hist_kernel<<<(E + 255) / 256, 256, 0, stream>>>(edst, deg_cnt, E);
    scan1_kernel<<<nScanB, 256, 0, stream>>>(deg_cnt, row_ptr, bsum, NN);
    scan2_kernel<<<1, 256, 0, stream>>>(bsum, nScanB);
    scan3_kernel<<<nScanB, 256, 0, stream>>>(row_ptr, bsum, NN);
    fill_kernel<<<(E + 255) / 256, 256, 0, stream>>>(esrc, edst, row_ptr, cursor, sorted_src, E);
    dinv_kernel<<<(NN + 255) / 256, 256, 0, stream>>>(deg_cnt, dinv, NN);

    // 3. knn graph from h0 (hi/lo split, reg-A + dbuf-B fused sim+topk)
    row_norm_hl<<<NN, 256, 0, stream>>>(B0, xnh, xnl);
    simtopk<<<832, 256, 0, stream>>>(xnh, xnl, fsrc);

    // 4. layers
    float* h  = B0;
    float* mb = B1;
    dim3 ngrid(GG, 8);
    for (int i = 0; i < 2; ++i) {
        const ushort* Wc = (i == 0) ? convWt0 : convWt1;
        const ushort* Wf = (i == 0) ? fconvWt0 : fconvWt1;
        const float* bc  = conv_b  + (size_t)i * HH;
        const float* bf  = fconv_b + (size_t)i * HH;
        // h-road conv -> bf16 messages
        gemm_mfma<<<ggrid, 256, 0, stream>>>(h, nullptr, Wc, nullptr, nullptr, msgbf,
                                             NN, HH, HH, 2, nullptr, nullptr, nullptr);
        gcn_gather<<<gatherGrid, 256, 0, stream>>>(msgbf, row_ptr, deg_cnt, sorted_src,
                                                   dinv, bc, B2);
        hipMemsetAsync(S1, 0, (size_t)2 * GG * HH * 4, stream);
        norm_stats<<<ngrid, 256, 0, stream>>>(B2, S1, S2);
        norm_apply<<<NN, 256, 0, stream>>>(B2, S1, S2, norm_w + i * HH, norm_b + i * HH,
                                           norm_ms + i * HH);
        // f-road conv (knn graph) -> bf16 messages
        gemm_mfma<<<ggrid, 256, 0, stream>>>(B2, nullptr, Wf, nullptr, nullptr, msgbf,
                                             NN, HH, HH, 2, nullptr, nullptr, nullptr);
        fgcn_gather<<<gatherGrid, 256, 0, stream>>>(msgbf, fsrc, bf, B3);
        hipMemsetAsync(S1, 0, (size_t)2 * GG * HH * 4, stream);
        norm_stats<<<ngrid, 256, 0, stream>>>(B3, S1, S2);
        norm_apply<<<NN, 256, 0, stream>>>(B3, S1, S2, fnorm_w + i * HH, fnorm_b + i * HH,
                                           fnorm_ms + i * HH);
        // gate + combine
        gemm_mfma<<<ggrid, 256, 0, stream>>>(B2, B3, gateWt, gate_b, mb, nullptr,
                                             NN, 2 * HH, HH, 1, B2, B3, h);
        float* t = h; h = mb; mb = t;
    }
    // h = all_x[1], mb = all_x[0]
    pool_kernel<<<GG, 256, 0, stream>>>(mb, h, (float*)d_out);
}